// Round 5
// baseline (3759.544 us; speedup 1.0000x reference)
//
#include <hip/hip_runtime.h>
#include <hip/hip_bf16.h>
#include <math.h>

// Problem constants (fixed by the reference)
#define GN 100000   // nodes
#define GE 1200000  // edges
#define GB 128      // graphs
#define GF 92       // raw features
#define GD 64       // hidden dim
#define GL 3        // CGConv layers
#define GZ 129      // 2*D+1

#define CH 32       // nodes per wave in dense kernels

// round-to-nearest-even fp32 -> bf16 (returned in low 16 bits)
__device__ __forceinline__ unsigned int f2bf_rne(float x)
{
    unsigned int u = __float_as_uint(x);
    u += 0x7fffu + ((u >> 16) & 1u);
    return u >> 16;
}

// 64-K dot: h row via wave-uniform float4 VMEM loads, weights per-lane in VGPRs.
__device__ __forceinline__ float dot64(const float4* __restrict__ hr,
                                       const float (&w)[64], float a)
{
#pragma unroll
    for (int c = 0; c < 16; ++c) {
        float4 v = hr[c];
        a = fmaf(v.x, w[4 * c + 0], a);
        a = fmaf(v.y, w[4 * c + 1], a);
        a = fmaf(v.z, w[4 * c + 2], a);
        a = fmaf(v.w, w[4 * c + 3], a);
    }
    return a;
}

// dual-gate 64-K dot (F and S share the h row loads)
__device__ __forceinline__ void dot64x2(const float4* __restrict__ hr,
                                        const float (&wf)[64], const float (&ws)[64],
                                        float& f, float& s)
{
#pragma unroll
    for (int c = 0; c < 16; ++c) {
        float4 v = hr[c];
        f = fmaf(v.x, wf[4 * c + 0], f);
        f = fmaf(v.y, wf[4 * c + 1], f);
        f = fmaf(v.z, wf[4 * c + 2], f);
        f = fmaf(v.w, wf[4 * c + 3], f);
        s = fmaf(v.x, ws[4 * c + 0], s);
        s = fmaf(v.y, ws[4 * c + 1], s);
        s = fmaf(v.z, ws[4 * c + 2], s);
        s = fmaf(v.w, ws[4 * c + 3], s);
    }
}

// ---------------------------------------------------------------------------
// Fused pre-MLP (3 layers) + P0 + Q0.
// R15: weights-in-VGPR / lane=column. VALUBusy was pinned at ~30% across
// R12/R13/R14 because wave-uniform LDS broadcast of weights oversubscribes
// the shared LDS pipe ~3x vs VALU. Now: lane j holds weight column j in
// registers (coalesced global loads, once per phase per wave); h rows are
// wave-uniform float4 VMEM loads (TA pipe, otherwise idle). Zero LDS, zero
// syncthreads; each wave owns CH=32 nodes end-to-end. Layers ping-pong
// hA -> hB -> hA (distinct __restrict__ -> no false serialization).
// FMA order (k ascending, x..w) identical to R12-R14 -> bitwise-same.
// ---------------------------------------------------------------------------
__global__ __launch_bounds__(256, 3) void premlp_kernel(
    const float* __restrict__ X,
    const float* __restrict__ W0, const float* __restrict__ b0,
    const float* __restrict__ W1, const float* __restrict__ b1,
    const float* __restrict__ W2, const float* __restrict__ b2,
    const float* __restrict__ WfD, const float* __restrict__ WsD,   // rows 0..63
    const float* __restrict__ WfS, const float* __restrict__ WsS,   // rows 64..127
    const float* __restrict__ bf, const float* __restrict__ bs,
    float* __restrict__ ha, float* __restrict__ hb,
    unsigned int* __restrict__ Pout, float* __restrict__ Qout, int N)
{
    const int lane = threadIdx.x & 63;
    const int base = (blockIdx.x * 4 + (threadIdx.x >> 6)) * CH;
    if (base >= N) return;

    // ---- L0: X (K=92) @ W0 + b0, relu -> ha ----
    {
        float w[92];
#pragma unroll
        for (int k = 0; k < 92; ++k) w[k] = W0[k * 64 + lane];
        const float bias = b0[lane];
        for (int r = 0; r < CH; r += 2) {
            const int n0 = base + r, n1 = base + r + 1;
            const float4* __restrict__ x0 =
                (const float4*)(X + (size_t)((n0 < N) ? n0 : N - 1) * GF);
            const float4* __restrict__ x1 =
                (const float4*)(X + (size_t)((n1 < N) ? n1 : N - 1) * GF);
            float a0 = bias, a1 = bias;
#pragma unroll
            for (int c = 0; c < 23; ++c) {
                float4 v0 = x0[c], v1 = x1[c];
                a0 = fmaf(v0.x, w[4 * c + 0], a0);
                a0 = fmaf(v0.y, w[4 * c + 1], a0);
                a0 = fmaf(v0.z, w[4 * c + 2], a0);
                a0 = fmaf(v0.w, w[4 * c + 3], a0);
                a1 = fmaf(v1.x, w[4 * c + 0], a1);
                a1 = fmaf(v1.y, w[4 * c + 1], a1);
                a1 = fmaf(v1.z, w[4 * c + 2], a1);
                a1 = fmaf(v1.w, w[4 * c + 3], a1);
            }
            if (n0 < N) ha[(size_t)n0 * 64 + lane] = fmaxf(a0, 0.f);
            if (n1 < N) ha[(size_t)n1 * 64 + lane] = fmaxf(a1, 0.f);
        }
    }
    asm volatile("s_waitcnt vmcnt(0)" ::: "memory");

    // ---- L1: ha @ W1 + b1, relu -> hb ----
    {
        float w[64];
#pragma unroll
        for (int k = 0; k < 64; ++k) w[k] = W1[k * 64 + lane];
        const float bias = b1[lane];
        for (int r = 0; r < CH; r += 2) {
            const int n0 = base + r, n1 = base + r + 1;
            const float4* __restrict__ h0 =
                (const float4*)(ha + (size_t)((n0 < N) ? n0 : N - 1) * 64);
            const float4* __restrict__ h1 =
                (const float4*)(ha + (size_t)((n1 < N) ? n1 : N - 1) * 64);
            float a0 = dot64(h0, w, bias);
            float a1 = dot64(h1, w, bias);
            if (n0 < N) hb[(size_t)n0 * 64 + lane] = fmaxf(a0, 0.f);
            if (n1 < N) hb[(size_t)n1 * 64 + lane] = fmaxf(a1, 0.f);
        }
    }
    asm volatile("s_waitcnt vmcnt(0)" ::: "memory");

    // ---- L2: hb @ W2 + b2, relu -> ha (final h) ----
    {
        float w[64];
#pragma unroll
        for (int k = 0; k < 64; ++k) w[k] = W2[k * 64 + lane];
        const float bias = b2[lane];
        for (int r = 0; r < CH; r += 2) {
            const int n0 = base + r, n1 = base + r + 1;
            const float4* __restrict__ h0 =
                (const float4*)(hb + (size_t)((n0 < N) ? n0 : N - 1) * 64);
            const float4* __restrict__ h1 =
                (const float4*)(hb + (size_t)((n1 < N) ? n1 : N - 1) * 64);
            float a0 = dot64(h0, w, bias);
            float a1 = dot64(h1, w, bias);
            if (n0 < N) ha[(size_t)n0 * 64 + lane] = fmaxf(a0, 0.f);
            if (n1 < N) ha[(size_t)n1 * 64 + lane] = fmaxf(a1, 0.f);
        }
    }
    asm volatile("s_waitcnt vmcnt(0)" ::: "memory");

    // ---- P0: src-half gates (WfS/WsS), packed bf16 -> Pout ----
    {
        float wf[64], ws[64];
#pragma unroll
        for (int k = 0; k < 64; ++k) {
            wf[k] = WfS[k * 64 + lane];
            ws[k] = WsS[k * 64 + lane];
        }
        for (int r = 0; r < CH; r += 2) {
            const int n0 = base + r, n1 = base + r + 1;
            const float4* __restrict__ h0 =
                (const float4*)(ha + (size_t)((n0 < N) ? n0 : N - 1) * 64);
            const float4* __restrict__ h1 =
                (const float4*)(ha + (size_t)((n1 < N) ? n1 : N - 1) * 64);
            float f0 = 0.f, s0 = 0.f, f1 = 0.f, s1 = 0.f;
            dot64x2(h0, wf, ws, f0, s0);
            dot64x2(h1, wf, ws, f1, s1);
            if (n0 < N) Pout[(size_t)n0 * 64 + lane] = f2bf_rne(f0) | (f2bf_rne(s0) << 16);
            if (n1 < N) Pout[(size_t)n1 * 64 + lane] = f2bf_rne(f1) | (f2bf_rne(s1) << 16);
        }
    }

    // ---- Q0: dst-half gates (WfD/WsD) + bias, fp32 (qf,qs) pairs -> Qout ----
    {
        float wf[64], ws[64];
#pragma unroll
        for (int k = 0; k < 64; ++k) {
            wf[k] = WfD[k * 64 + lane];
            ws[k] = WsD[k * 64 + lane];
        }
        const float bfj = bf[lane], bsj = bs[lane];
        for (int r = 0; r < CH; r += 2) {
            const int n0 = base + r, n1 = base + r + 1;
            const float4* __restrict__ h0 =
                (const float4*)(ha + (size_t)((n0 < N) ? n0 : N - 1) * 64);
            const float4* __restrict__ h1 =
                (const float4*)(ha + (size_t)((n1 < N) ? n1 : N - 1) * 64);
            float f0 = bfj, s0 = bsj, f1 = bfj, s1 = bsj;
            dot64x2(h0, wf, ws, f0, s0);
            dot64x2(h1, wf, ws, f1, s1);
            if (n0 < N) ((float2*)Qout)[(size_t)n0 * 64 + lane] = make_float2(f0, s0);
            if (n1 < N) ((float2*)Qout)[(size_t)n1 * 64 + lane] = make_float2(f1, s1);
        }
    }
}

// ---------------------------------------------------------------------------
// Gate projections for one CGConv layer: P (src half, packed bf16) and
// Q (dst half + bias, fp32 (qf,qs) pairs).
// R15: same weights-in-VGPR / lane=column structure as premlp. Input h is
// read-only -> no hazards, no waits at all.
// ---------------------------------------------------------------------------
__global__ __launch_bounds__(256, 3) void pjq_kernel(
    const float* __restrict__ h,
    const float* __restrict__ Wf, const float* __restrict__ Ws,
    const float* __restrict__ bfv, const float* __restrict__ bsv,
    unsigned int* __restrict__ P, float* __restrict__ Q, int N)
{
    const int lane = threadIdx.x & 63;
    const int base = (blockIdx.x * 4 + (threadIdx.x >> 6)) * CH;
    if (base >= N) return;

    // ---- P: rows 64..127 ----
    {
        float wf[64], ws[64];
#pragma unroll
        for (int k = 0; k < 64; ++k) {
            wf[k] = Wf[(64 + k) * 64 + lane];
            ws[k] = Ws[(64 + k) * 64 + lane];
        }
        for (int r = 0; r < CH; r += 2) {
            const int n0 = base + r, n1 = base + r + 1;
            const float4* __restrict__ h0 =
                (const float4*)(h + (size_t)((n0 < N) ? n0 : N - 1) * 64);
            const float4* __restrict__ h1 =
                (const float4*)(h + (size_t)((n1 < N) ? n1 : N - 1) * 64);
            float f0 = 0.f, s0 = 0.f, f1 = 0.f, s1 = 0.f;
            dot64x2(h0, wf, ws, f0, s0);
            dot64x2(h1, wf, ws, f1, s1);
            if (n0 < N) P[(size_t)n0 * 64 + lane] = f2bf_rne(f0) | (f2bf_rne(s0) << 16);
            if (n1 < N) P[(size_t)n1 * 64 + lane] = f2bf_rne(f1) | (f2bf_rne(s1) << 16);
        }
    }

    // ---- Q: rows 0..63 + bias ----
    {
        float wf[64], ws[64];
#pragma unroll
        for (int k = 0; k < 64; ++k) {
            wf[k] = Wf[k * 64 + lane];
            ws[k] = Ws[k * 64 + lane];
        }
        const float bfj = bfv[lane], bsj = bsv[lane];
        for (int r = 0; r < CH; r += 2) {
            const int n0 = base + r, n1 = base + r + 1;
            const float4* __restrict__ h0 =
                (const float4*)(h + (size_t)((n0 < N) ? n0 : N - 1) * 64);
            const float4* __restrict__ h1 =
                (const float4*)(h + (size_t)((n1 < N) ? n1 : N - 1) * 64);
            float f0 = bfj, s0 = bsj, f1 = bfj, s1 = bsj;
            dot64x2(h0, wf, ws, f0, s0);
            dot64x2(h1, wf, ws, f1, s1);
            if (n0 < N) ((float2*)Q)[(size_t)n0 * 64 + lane] = make_float2(f0, s0);
            if (n1 < N) ((float2*)Q)[(size_t)n1 * 64 + lane] = make_float2(f1, s1);
        }
    }
}

// ---------------------------------------------------------------------------
// In-degree histogram (int)
// ---------------------------------------------------------------------------
__global__ __launch_bounds__(256) void deg_kernel(
    const int* __restrict__ dst, int* __restrict__ deg, int E)
{
    int e = blockIdx.x * blockDim.x + threadIdx.x;
    if (e < E) atomicAdd(&deg[dst[e]], 1);
}

// ---------------------------------------------------------------------------
// Three-phase exclusive scan over deg -> rowptr, cursor
// ---------------------------------------------------------------------------
__global__ __launch_bounds__(1024) void scanA_kernel(
    const int* __restrict__ deg, int* __restrict__ iscan,
    int* __restrict__ bsum, int N)
{
    __shared__ int lds[1024];
    int tid = threadIdx.x;
    int gid = blockIdx.x * 1024 + tid;
    int v = (gid < N) ? deg[gid] : 0;
    lds[tid] = v; __syncthreads();
    for (int off = 1; off < 1024; off <<= 1) {
        int t = (tid >= off) ? lds[tid - off] : 0;
        __syncthreads();
        lds[tid] += t;
        __syncthreads();
    }
    if (gid < N) iscan[gid] = lds[tid];
    if (tid == 1023) bsum[blockIdx.x] = lds[1023];
}

__global__ __launch_bounds__(128) void scanB_kernel(
    const int* __restrict__ bsum, int* __restrict__ boff, int nb)
{
    __shared__ int lds[128];
    int t = threadIdx.x;
    int v = (t < nb) ? bsum[t] : 0;
    lds[t] = v; __syncthreads();
    for (int off = 1; off < 128; off <<= 1) {
        int u = (t >= off) ? lds[t - off] : 0;
        __syncthreads();
        lds[t] += u;
        __syncthreads();
    }
    if (t < nb) boff[t] = lds[t] - v;  // exclusive
}

__global__ __launch_bounds__(256) void scanC_kernel(
    const int* __restrict__ iscan, const int* __restrict__ boff,
    const int* __restrict__ deg,
    int* __restrict__ rowptr, int* __restrict__ cursor, int N)
{
    int i = blockIdx.x * blockDim.x + threadIdx.x;
    if (i >= N) return;
    int incl = iscan[i] + boff[i >> 10];
    rowptr[i + 1] = incl;
    cursor[i] = incl - deg[i];
    if (i == 0) rowptr[0] = 0;
}

// ---------------------------------------------------------------------------
// Edge scatter into CSR order, packed (src, ea) int2
// ---------------------------------------------------------------------------
__global__ __launch_bounds__(256) void escatter_kernel(
    const int* __restrict__ src, const int* __restrict__ dst,
    const float* __restrict__ ea, int* __restrict__ cursor,
    int2* __restrict__ e_se, int E)
{
    int e = blockIdx.x * blockDim.x + threadIdx.x;
    if (e >= E) return;
    int pos = atomicAdd(&cursor[dst[e]], 1);
    e_se[pos] = make_int2(src[e], __float_as_int(ea[e]));
}

// ---------------------------------------------------------------------------
// CGConv edge pass. One wave per node, lane = dim. Q precomputed (R12).
// ---------------------------------------------------------------------------
__global__ __launch_bounds__(256) void edge_kernel(
    const float* __restrict__ h, const int* __restrict__ rowptr,
    const int2* __restrict__ e_se,
    const unsigned int* __restrict__ P,
    const float* __restrict__ Q,
    const float* __restrict__ Wf, const float* __restrict__ Ws,
    float* __restrict__ hout)
{
    int n = blockIdx.x * 4 + (threadIdx.x >> 6);   // grid exactly covers GN
    int d = threadIdx.x & 63;

    const float2 qv = ((const float2*)Q)[(size_t)n * 64 + d];
    float qf = qv.x, qs = qv.y;
    float wf = Wf[128 * 64 + d];
    float ws = Ws[128 * 64 + d];

    size_t idx = (size_t)n * 64 + d;
    float hres = h[idx];

    int rb = rowptr[n], re = rowptr[n + 1];
    float agg = 0.f;
#pragma unroll 8
    for (int p = rb; p < re; ++p) {
        int2 se = e_se[p];         // wave-uniform 8B load
        int s = se.x;
        float ea = __int_as_float(se.y);
        unsigned int pv = P[(size_t)s * 64 + d];   // gathered dword (256B/wave)
        float pf = __uint_as_float(pv << 16);
        float psv = __uint_as_float(pv & 0xffff0000u);
        float xF = fmaf(ea, wf, qf + pf);
        float xS = fmaf(ea, ws, qs + psv);
        float sig = __builtin_amdgcn_rcpf(1.f + __expf(-xF));
        float t = __expf(-fabsf(xS));
        float sp = fmaxf(xS, 0.f) + __logf(1.f + t);
        agg = fmaf(sig, sp, agg);
    }

    float inv = 1.f / (float)max(re - rb, 1);
    hout[idx] = fmaxf(hres + agg * inv, 0.f);
}

// ---------------------------------------------------------------------------
// Graph segment starts: bm sorted; gstart[b] = first node of graph b.
// ---------------------------------------------------------------------------
__global__ __launch_bounds__(256) void gstart_kernel(
    const int* __restrict__ bm, int* __restrict__ gstart, int N)
{
    int i = blockIdx.x * blockDim.x + threadIdx.x;
    if (i >= N) return;
    int b = bm[i];
    int prev = (i == 0) ? -1 : bm[i - 1];
    for (int g = prev + 1; g <= b; ++g) gstart[g] = i;
    if (i == N - 1)
        for (int g = b + 1; g <= GB; ++g) gstart[g] = N;
}

// ---------------------------------------------------------------------------
// Segmented mean pool: one block per graph, no atomics.
// ---------------------------------------------------------------------------
__global__ __launch_bounds__(256) void pool_seg_kernel(
    const float* __restrict__ h, const int* __restrict__ gstart,
    float* __restrict__ g)
{
    int b = blockIdx.x;
    int s = gstart[b], e = gstart[b + 1];
    int d = threadIdx.x & 63;
    int w = threadIdx.x >> 6;
    float acc = 0.f;
    for (int n = s + w; n < e; n += 4)
        acc += h[(size_t)n * 64 + d];
    __shared__ float lds[256];
    lds[threadIdx.x] = acc;
    __syncthreads();
    if (w == 0) {
        acc = lds[d] + lds[64 + d] + lds[128 + d] + lds[192 + d];
        g[b * 64 + d] = acc / fmaxf((float)(e - s), 1.f);
    }
}

// ---------------------------------------------------------------------------
// Fused post-MLP (3 relu layers) + final dot + bias. One wave per graph.
// ---------------------------------------------------------------------------
__global__ __launch_bounds__(256) void postmlp_kernel(
    const float* __restrict__ g,
    const float* __restrict__ W0, const float* __restrict__ b0,
    const float* __restrict__ W1, const float* __restrict__ b1,
    const float* __restrict__ W2, const float* __restrict__ b2,
    const float* __restrict__ Wfin, const float* __restrict__ bfin,
    float* __restrict__ out)
{
    int b = blockIdx.x * 4 + (threadIdx.x >> 6);   // 32 blocks x 4 waves = 128
    int d = threadIdx.x & 63;
    float h = g[(size_t)b * 64 + d];

    float acc = b0[d];
#pragma unroll
    for (int k = 0; k < 64; ++k)
        acc = fmaf(__shfl(h, k, 64), W0[k * 64 + d], acc);
    h = fmaxf(acc, 0.f);

    acc = b1[d];
#pragma unroll
    for (int k = 0; k < 64; ++k)
        acc = fmaf(__shfl(h, k, 64), W1[k * 64 + d], acc);
    h = fmaxf(acc, 0.f);

    acc = b2[d];
#pragma unroll
    for (int k = 0; k < 64; ++k)
        acc = fmaf(__shfl(h, k, 64), W2[k * 64 + d], acc);
    h = fmaxf(acc, 0.f);

    float v = h * Wfin[d];
#pragma unroll
    for (int off = 32; off >= 1; off >>= 1)
        v += __shfl_xor(v, off, 64);
    if (d == 0) out[b] = v + bfin[0];
}

extern "C" void kernel_launch(void* const* d_in, const int* in_sizes, int n_in,
                              void* d_out, int out_size, void* d_ws, size_t ws_size,
                              hipStream_t stream)
{
    const float* X      = (const float*)d_in[0];
    const int*   eidx   = (const int*)d_in[1];
    const float* ea     = (const float*)d_in[3];
    const int*   bm     = (const int*)d_in[4];
    const float* pre_W0 = (const float*)d_in[5];
    const float* pre_b0 = (const float*)d_in[6];
    const float* pre_W1 = (const float*)d_in[7];
    const float* pre_b1 = (const float*)d_in[8];
    const float* pre_W2 = (const float*)d_in[9];
    const float* pre_b2 = (const float*)d_in[10];
    const float* cg_Wf  = (const float*)d_in[11];
    const float* cg_bf  = (const float*)d_in[12];
    const float* cg_Ws  = (const float*)d_in[13];
    const float* cg_bs  = (const float*)d_in[14];
    const float* post_W0 = (const float*)d_in[15];
    const float* post_b0 = (const float*)d_in[16];
    const float* post_W1 = (const float*)d_in[17];
    const float* post_b1 = (const float*)d_in[18];
    const float* post_W2 = (const float*)d_in[19];
    const float* post_b2 = (const float*)d_in[20];
    const float* post_Wf = (const float*)d_in[21];
    const float* post_bf = (const float*)d_in[22];

    const int* src = eidx;
    const int* dst = eidx + GE;

    // ---- workspace carve-up ----
    const size_t N64 = (size_t)GN * 64;
    float* hA    = (float*)d_ws;            // N*64
    float* hB    = hA + N64;                // N*64
    unsigned int* P = (unsigned int*)(hB + N64);  // N*64 packed bf16x2
    int* deg_i   = (int*)(P + N64);         // N
    int* iscan   = deg_i + GN;              // N
    int* bsum    = iscan + GN;              // 128
    int* boff    = bsum + 128;              // 128
    int* rowptr  = boff + 128;              // N+2 (padded so e_se is 8B-aligned)
    int* cursor  = rowptr + GN + 2;         // N
    int2* e_se   = (int2*)(cursor + GN);    // E int2 (8B-aligned)
    int* gstart  = (int*)(e_se + GE);       // B+1
    float* g0    = (float*)(gstart + GB + 1); // B*64 (8192 floats, keeps 8B align)
    float* Q     = g0 + (size_t)GB * 64;    // N*128 fp32 (qf,qs) pairs

    const int TPB = 256;
    int gridE  = (GE + TPB - 1) / TPB;
    int gridN  = (GN + TPB - 1) / TPB;         // 391 (lane=node grid)
    int gridP  = (GN + 127) / 128;             // 782 (4 waves x 32 nodes per block)
    int gridND = ((GN * 64) + TPB - 1) / TPB;  // 25000 (edge grid)
    int scanBlocks = (GN + 1023) / 1024;       // 98

    // per-layer weight pointers
    const float* Wf0 = cg_Wf;
    const float* Ws0 = cg_Ws;
    const float* Wf1 = cg_Wf + (size_t)1 * GZ * GD;
    const float* Ws1 = cg_Ws + (size_t)1 * GZ * GD;
    const float* Wf2 = cg_Wf + (size_t)2 * GZ * GD;
    const float* Ws2 = cg_Ws + (size_t)2 * GZ * GD;

    // fused pre-MLP (weights-in-VGPR, hB as ping-pong scratch) + P0 + Q0
    premlp_kernel<<<gridP, TPB, 0, stream>>>(
        X, pre_W0, pre_b0, pre_W1, pre_b1, pre_W2, pre_b2,
        Wf0, Ws0, Wf0 + 64 * 64, Ws0 + 64 * 64, cg_bf, cg_bs,
        hA, hB, P, Q, GN);

    // degree + CSR build
    hipMemsetAsync(deg_i, 0, GN * sizeof(int), stream);
    deg_kernel<<<gridE, TPB, 0, stream>>>(dst, deg_i, GE);
    scanA_kernel<<<scanBlocks, 1024, 0, stream>>>(deg_i, iscan, bsum, GN);
    scanB_kernel<<<1, 128, 0, stream>>>(bsum, boff, scanBlocks);
    scanC_kernel<<<gridN, TPB, 0, stream>>>(iscan, boff, deg_i, rowptr, cursor, GN);
    escatter_kernel<<<gridE, TPB, 0, stream>>>(src, dst, ea, cursor, e_se, GE);

    // graph segment starts (bm sorted)
    gstart_kernel<<<gridN, TPB, 0, stream>>>(bm, gstart, GN);

    // CGConv layers: lean edge pass + fused P/Q projection for next layer
    edge_kernel<<<gridND, TPB, 0, stream>>>(
        hA, rowptr, e_se, P, Q, Wf0, Ws0, hB);
    pjq_kernel<<<gridP, TPB, 0, stream>>>(
        hB, Wf1, Ws1, cg_bf + GD, cg_bs + GD, P, Q, GN);
    edge_kernel<<<gridND, TPB, 0, stream>>>(
        hB, rowptr, e_se, P, Q, Wf1, Ws1, hA);
    pjq_kernel<<<gridP, TPB, 0, stream>>>(
        hA, Wf2, Ws2, cg_bf + 2 * GD, cg_bs + 2 * GD, P, Q, GN);
    edge_kernel<<<gridND, TPB, 0, stream>>>(
        hA, rowptr, e_se, P, Q, Wf2, Ws2, hB);

    // segmented mean pool (no atomics)
    pool_seg_kernel<<<GB, TPB, 0, stream>>>(hB, gstart, g0);

    // fused post-MLP + final projection
    postmlp_kernel<<<GB / 4, TPB, 0, stream>>>(
        g0, post_W0, post_b0, post_W1, post_b1, post_W2, post_b2,
        post_Wf, post_bf, (float*)d_out);
}

// Round 6
// 1891.198 us; speedup vs baseline: 1.9879x; 1.9879x over previous
//
#include <hip/hip_runtime.h>
#include <hip/hip_bf16.h>
#include <math.h>

// Problem constants (fixed by the reference)
#define GN 100000   // nodes
#define GE 1200000  // edges
#define GB 128      // graphs
#define GF 92       // raw features
#define GD 64       // hidden dim
#define GL 3        // CGConv layers
#define GZ 129      // 2*D+1

#define CH 32       // nodes per wave in dense kernels

// round-to-nearest-even fp32 -> bf16 (returned in low 16 bits)
__device__ __forceinline__ unsigned int f2bf_rne(float x)
{
    unsigned int u = __float_as_uint(x);
    u += 0x7fffu + ((u >> 16) & 1u);
    return u >> 16;
}

// 64-K dot: h row via wave-uniform float4 VMEM loads, weights per-lane in VGPRs.
__device__ __forceinline__ float dot64(const float4* __restrict__ hr,
                                       const float (&w)[64], float a)
{
#pragma unroll
    for (int c = 0; c < 16; ++c) {
        float4 v = hr[c];
        a = fmaf(v.x, w[4 * c + 0], a);
        a = fmaf(v.y, w[4 * c + 1], a);
        a = fmaf(v.z, w[4 * c + 2], a);
        a = fmaf(v.w, w[4 * c + 3], a);
    }
    return a;
}

// ---------------------------------------------------------------------------
// Fused pre-MLP (3 layers) + P0 + Q0.
// R15 theory: weights-in-VGPR / lane=column (VALUBusy was pinned ~30% across
// R12-R14 by wave-uniform LDS-broadcast weight delivery; VGPR delivery frees
// the LDS pipe entirely -- zero LDS, zero syncthreads).
// R16 fix: R15 spilled (VGPR cap 84 < w[92]/dual-gate 128 -> 1.88GB scratch
// traffic, VALUBusy 5.9%). Now __launch_bounds__(256,2) (128-VGPR cap) and
// every dual-gate phase split into separate F / S passes so peak live
// weight array is w[64] (~85 regs). P halves stored as ushorts (low=F,
// high=S -> same dword layout as before); Q halves as .x / .y floats.
// FMA order (k ascending, x..w) identical to R12-R15 -> bitwise-same.
// ---------------------------------------------------------------------------
__global__ __launch_bounds__(256, 2) void premlp_kernel(
    const float* __restrict__ X,
    const float* __restrict__ W0, const float* __restrict__ b0,
    const float* __restrict__ W1, const float* __restrict__ b1,
    const float* __restrict__ W2, const float* __restrict__ b2,
    const float* __restrict__ WfD, const float* __restrict__ WsD,   // rows 0..63
    const float* __restrict__ WfS, const float* __restrict__ WsS,   // rows 64..127
    const float* __restrict__ bf, const float* __restrict__ bs,
    float* __restrict__ ha, float* __restrict__ hb,
    unsigned int* __restrict__ Pout, float* __restrict__ Qout, int N)
{
    const int lane = threadIdx.x & 63;
    const int base = (blockIdx.x * 4 + (threadIdx.x >> 6)) * CH;
    if (base >= N) return;

    // ---- L0: X (K=92) @ W0 + b0, relu -> ha ----
    {
        float w[92];
#pragma unroll
        for (int k = 0; k < 92; ++k) w[k] = W0[k * 64 + lane];
        const float bias = b0[lane];
        for (int r = 0; r < CH; r += 2) {
            const int n0 = base + r, n1 = base + r + 1;
            const float4* __restrict__ x0 =
                (const float4*)(X + (size_t)((n0 < N) ? n0 : N - 1) * GF);
            const float4* __restrict__ x1 =
                (const float4*)(X + (size_t)((n1 < N) ? n1 : N - 1) * GF);
            float a0 = bias, a1 = bias;
#pragma unroll
            for (int c = 0; c < 23; ++c) {
                float4 v0 = x0[c], v1 = x1[c];
                a0 = fmaf(v0.x, w[4 * c + 0], a0);
                a0 = fmaf(v0.y, w[4 * c + 1], a0);
                a0 = fmaf(v0.z, w[4 * c + 2], a0);
                a0 = fmaf(v0.w, w[4 * c + 3], a0);
                a1 = fmaf(v1.x, w[4 * c + 0], a1);
                a1 = fmaf(v1.y, w[4 * c + 1], a1);
                a1 = fmaf(v1.z, w[4 * c + 2], a1);
                a1 = fmaf(v1.w, w[4 * c + 3], a1);
            }
            if (n0 < N) ha[(size_t)n0 * 64 + lane] = fmaxf(a0, 0.f);
            if (n1 < N) ha[(size_t)n1 * 64 + lane] = fmaxf(a1, 0.f);
        }
    }
    asm volatile("s_waitcnt vmcnt(0)" ::: "memory");

    // ---- L1: ha @ W1 + b1, relu -> hb ----
    {
        float w[64];
#pragma unroll
        for (int k = 0; k < 64; ++k) w[k] = W1[k * 64 + lane];
        const float bias = b1[lane];
        for (int r = 0; r < CH; r += 2) {
            const int n0 = base + r, n1 = base + r + 1;
            const float4* __restrict__ h0 =
                (const float4*)(ha + (size_t)((n0 < N) ? n0 : N - 1) * 64);
            const float4* __restrict__ h1 =
                (const float4*)(ha + (size_t)((n1 < N) ? n1 : N - 1) * 64);
            float a0 = dot64(h0, w, bias);
            float a1 = dot64(h1, w, bias);
            if (n0 < N) hb[(size_t)n0 * 64 + lane] = fmaxf(a0, 0.f);
            if (n1 < N) hb[(size_t)n1 * 64 + lane] = fmaxf(a1, 0.f);
        }
    }
    asm volatile("s_waitcnt vmcnt(0)" ::: "memory");

    // ---- L2: hb @ W2 + b2, relu -> ha (final h) ----
    {
        float w[64];
#pragma unroll
        for (int k = 0; k < 64; ++k) w[k] = W2[k * 64 + lane];
        const float bias = b2[lane];
        for (int r = 0; r < CH; r += 2) {
            const int n0 = base + r, n1 = base + r + 1;
            const float4* __restrict__ h0 =
                (const float4*)(hb + (size_t)((n0 < N) ? n0 : N - 1) * 64);
            const float4* __restrict__ h1 =
                (const float4*)(hb + (size_t)((n1 < N) ? n1 : N - 1) * 64);
            float a0 = dot64(h0, w, bias);
            float a1 = dot64(h1, w, bias);
            if (n0 < N) ha[(size_t)n0 * 64 + lane] = fmaxf(a0, 0.f);
            if (n1 < N) ha[(size_t)n1 * 64 + lane] = fmaxf(a1, 0.f);
        }
    }
    asm volatile("s_waitcnt vmcnt(0)" ::: "memory");

    unsigned short* __restrict__ Pus = (unsigned short*)Pout;

    // ---- P0-F: WfS, bf16 -> low ushort ----
    {
        float w[64];
#pragma unroll
        for (int k = 0; k < 64; ++k) w[k] = WfS[k * 64 + lane];
        for (int r = 0; r < CH; r += 2) {
            const int n0 = base + r, n1 = base + r + 1;
            const float4* __restrict__ h0 =
                (const float4*)(ha + (size_t)((n0 < N) ? n0 : N - 1) * 64);
            const float4* __restrict__ h1 =
                (const float4*)(ha + (size_t)((n1 < N) ? n1 : N - 1) * 64);
            float f0 = dot64(h0, w, 0.f);
            float f1 = dot64(h1, w, 0.f);
            if (n0 < N) Pus[((size_t)n0 * 64 + lane) * 2] = (unsigned short)f2bf_rne(f0);
            if (n1 < N) Pus[((size_t)n1 * 64 + lane) * 2] = (unsigned short)f2bf_rne(f1);
        }
    }

    // ---- P0-S: WsS, bf16 -> high ushort ----
    {
        float w[64];
#pragma unroll
        for (int k = 0; k < 64; ++k) w[k] = WsS[k * 64 + lane];
        for (int r = 0; r < CH; r += 2) {
            const int n0 = base + r, n1 = base + r + 1;
            const float4* __restrict__ h0 =
                (const float4*)(ha + (size_t)((n0 < N) ? n0 : N - 1) * 64);
            const float4* __restrict__ h1 =
                (const float4*)(ha + (size_t)((n1 < N) ? n1 : N - 1) * 64);
            float s0 = dot64(h0, w, 0.f);
            float s1 = dot64(h1, w, 0.f);
            if (n0 < N) Pus[((size_t)n0 * 64 + lane) * 2 + 1] = (unsigned short)f2bf_rne(s0);
            if (n1 < N) Pus[((size_t)n1 * 64 + lane) * 2 + 1] = (unsigned short)f2bf_rne(s1);
        }
    }

    // ---- Q0-F: WfD + bf -> Q .x ----
    {
        float w[64];
#pragma unroll
        for (int k = 0; k < 64; ++k) w[k] = WfD[k * 64 + lane];
        const float bfj = bf[lane];
        for (int r = 0; r < CH; r += 2) {
            const int n0 = base + r, n1 = base + r + 1;
            const float4* __restrict__ h0 =
                (const float4*)(ha + (size_t)((n0 < N) ? n0 : N - 1) * 64);
            const float4* __restrict__ h1 =
                (const float4*)(ha + (size_t)((n1 < N) ? n1 : N - 1) * 64);
            float f0 = dot64(h0, w, bfj);
            float f1 = dot64(h1, w, bfj);
            if (n0 < N) Qout[((size_t)n0 * 64 + lane) * 2] = f0;
            if (n1 < N) Qout[((size_t)n1 * 64 + lane) * 2] = f1;
        }
    }

    // ---- Q0-S: WsD + bs -> Q .y ----
    {
        float w[64];
#pragma unroll
        for (int k = 0; k < 64; ++k) w[k] = WsD[k * 64 + lane];
        const float bsj = bs[lane];
        for (int r = 0; r < CH; r += 2) {
            const int n0 = base + r, n1 = base + r + 1;
            const float4* __restrict__ h0 =
                (const float4*)(ha + (size_t)((n0 < N) ? n0 : N - 1) * 64);
            const float4* __restrict__ h1 =
                (const float4*)(ha + (size_t)((n1 < N) ? n1 : N - 1) * 64);
            float s0 = dot64(h0, w, bsj);
            float s1 = dot64(h1, w, bsj);
            if (n0 < N) Qout[((size_t)n0 * 64 + lane) * 2 + 1] = s0;
            if (n1 < N) Qout[((size_t)n1 * 64 + lane) * 2 + 1] = s1;
        }
    }
}

// ---------------------------------------------------------------------------
// Gate projections for one CGConv layer: P (src half, packed bf16) and
// Q (dst half + bias, fp32 (qf,qs) pairs).
// R16: weights-in-VGPR, single-gate passes (F/S split) -> no spill under
// the 128-VGPR cap. Input h read-only -> no hazards, no waits.
// ---------------------------------------------------------------------------
__global__ __launch_bounds__(256, 2) void pjq_kernel(
    const float* __restrict__ h,
    const float* __restrict__ Wf, const float* __restrict__ Ws,
    const float* __restrict__ bfv, const float* __restrict__ bsv,
    unsigned int* __restrict__ P, float* __restrict__ Q, int N)
{
    const int lane = threadIdx.x & 63;
    const int base = (blockIdx.x * 4 + (threadIdx.x >> 6)) * CH;
    if (base >= N) return;

    unsigned short* __restrict__ Pus = (unsigned short*)P;

    // ---- P-F: Wf rows 64..127 -> low ushort ----
    {
        float w[64];
#pragma unroll
        for (int k = 0; k < 64; ++k) w[k] = Wf[(64 + k) * 64 + lane];
        for (int r = 0; r < CH; r += 2) {
            const int n0 = base + r, n1 = base + r + 1;
            const float4* __restrict__ h0 =
                (const float4*)(h + (size_t)((n0 < N) ? n0 : N - 1) * 64);
            const float4* __restrict__ h1 =
                (const float4*)(h + (size_t)((n1 < N) ? n1 : N - 1) * 64);
            float f0 = dot64(h0, w, 0.f);
            float f1 = dot64(h1, w, 0.f);
            if (n0 < N) Pus[((size_t)n0 * 64 + lane) * 2] = (unsigned short)f2bf_rne(f0);
            if (n1 < N) Pus[((size_t)n1 * 64 + lane) * 2] = (unsigned short)f2bf_rne(f1);
        }
    }

    // ---- P-S: Ws rows 64..127 -> high ushort ----
    {
        float w[64];
#pragma unroll
        for (int k = 0; k < 64; ++k) w[k] = Ws[(64 + k) * 64 + lane];
        for (int r = 0; r < CH; r += 2) {
            const int n0 = base + r, n1 = base + r + 1;
            const float4* __restrict__ h0 =
                (const float4*)(h + (size_t)((n0 < N) ? n0 : N - 1) * 64);
            const float4* __restrict__ h1 =
                (const float4*)(h + (size_t)((n1 < N) ? n1 : N - 1) * 64);
            float s0 = dot64(h0, w, 0.f);
            float s1 = dot64(h1, w, 0.f);
            if (n0 < N) Pus[((size_t)n0 * 64 + lane) * 2 + 1] = (unsigned short)f2bf_rne(s0);
            if (n1 < N) Pus[((size_t)n1 * 64 + lane) * 2 + 1] = (unsigned short)f2bf_rne(s1);
        }
    }

    // ---- Q-F: Wf rows 0..63 + bf -> Q .x ----
    {
        float w[64];
#pragma unroll
        for (int k = 0; k < 64; ++k) w[k] = Wf[k * 64 + lane];
        const float bfj = bfv[lane];
        for (int r = 0; r < CH; r += 2) {
            const int n0 = base + r, n1 = base + r + 1;
            const float4* __restrict__ h0 =
                (const float4*)(h + (size_t)((n0 < N) ? n0 : N - 1) * 64);
            const float4* __restrict__ h1 =
                (const float4*)(h + (size_t)((n1 < N) ? n1 : N - 1) * 64);
            float f0 = dot64(h0, w, bfj);
            float f1 = dot64(h1, w, bfj);
            if (n0 < N) Q[((size_t)n0 * 64 + lane) * 2] = f0;
            if (n1 < N) Q[((size_t)n1 * 64 + lane) * 2] = f1;
        }
    }

    // ---- Q-S: Ws rows 0..63 + bs -> Q .y ----
    {
        float w[64];
#pragma unroll
        for (int k = 0; k < 64; ++k) w[k] = Ws[k * 64 + lane];
        const float bsj = bsv[lane];
        for (int r = 0; r < CH; r += 2) {
            const int n0 = base + r, n1 = base + r + 1;
            const float4* __restrict__ h0 =
                (const float4*)(h + (size_t)((n0 < N) ? n0 : N - 1) * 64);
            const float4* __restrict__ h1 =
                (const float4*)(h + (size_t)((n1 < N) ? n1 : N - 1) * 64);
            float s0 = dot64(h0, w, bsj);
            float s1 = dot64(h1, w, bsj);
            if (n0 < N) Q[((size_t)n0 * 64 + lane) * 2 + 1] = s0;
            if (n1 < N) Q[((size_t)n1 * 64 + lane) * 2 + 1] = s1;
        }
    }
}

// ---------------------------------------------------------------------------
// In-degree histogram (int)
// ---------------------------------------------------------------------------
__global__ __launch_bounds__(256) void deg_kernel(
    const int* __restrict__ dst, int* __restrict__ deg, int E)
{
    int e = blockIdx.x * blockDim.x + threadIdx.x;
    if (e < E) atomicAdd(&deg[dst[e]], 1);
}

// ---------------------------------------------------------------------------
// Three-phase exclusive scan over deg -> rowptr, cursor
// ---------------------------------------------------------------------------
__global__ __launch_bounds__(1024) void scanA_kernel(
    const int* __restrict__ deg, int* __restrict__ iscan,
    int* __restrict__ bsum, int N)
{
    __shared__ int lds[1024];
    int tid = threadIdx.x;
    int gid = blockIdx.x * 1024 + tid;
    int v = (gid < N) ? deg[gid] : 0;
    lds[tid] = v; __syncthreads();
    for (int off = 1; off < 1024; off <<= 1) {
        int t = (tid >= off) ? lds[tid - off] : 0;
        __syncthreads();
        lds[tid] += t;
        __syncthreads();
    }
    if (gid < N) iscan[gid] = lds[tid];
    if (tid == 1023) bsum[blockIdx.x] = lds[1023];
}

__global__ __launch_bounds__(128) void scanB_kernel(
    const int* __restrict__ bsum, int* __restrict__ boff, int nb)
{
    __shared__ int lds[128];
    int t = threadIdx.x;
    int v = (t < nb) ? bsum[t] : 0;
    lds[t] = v; __syncthreads();
    for (int off = 1; off < 128; off <<= 1) {
        int u = (t >= off) ? lds[t - off] : 0;
        __syncthreads();
        lds[t] += u;
        __syncthreads();
    }
    if (t < nb) boff[t] = lds[t] - v;  // exclusive
}

__global__ __launch_bounds__(256) void scanC_kernel(
    const int* __restrict__ iscan, const int* __restrict__ boff,
    const int* __restrict__ deg,
    int* __restrict__ rowptr, int* __restrict__ cursor, int N)
{
    int i = blockIdx.x * blockDim.x + threadIdx.x;
    if (i >= N) return;
    int incl = iscan[i] + boff[i >> 10];
    rowptr[i + 1] = incl;
    cursor[i] = incl - deg[i];
    if (i == 0) rowptr[0] = 0;
}

// ---------------------------------------------------------------------------
// Edge scatter into CSR order, packed (src, ea) int2
// ---------------------------------------------------------------------------
__global__ __launch_bounds__(256) void escatter_kernel(
    const int* __restrict__ src, const int* __restrict__ dst,
    const float* __restrict__ ea, int* __restrict__ cursor,
    int2* __restrict__ e_se, int E)
{
    int e = blockIdx.x * blockDim.x + threadIdx.x;
    if (e >= E) return;
    int pos = atomicAdd(&cursor[dst[e]], 1);
    e_se[pos] = make_int2(src[e], __float_as_int(ea[e]));
}

// ---------------------------------------------------------------------------
// CGConv edge pass. One wave per node, lane = dim. Q precomputed (R12).
// ---------------------------------------------------------------------------
__global__ __launch_bounds__(256) void edge_kernel(
    const float* __restrict__ h, const int* __restrict__ rowptr,
    const int2* __restrict__ e_se,
    const unsigned int* __restrict__ P,
    const float* __restrict__ Q,
    const float* __restrict__ Wf, const float* __restrict__ Ws,
    float* __restrict__ hout)
{
    int n = blockIdx.x * 4 + (threadIdx.x >> 6);   // grid exactly covers GN
    int d = threadIdx.x & 63;

    const float2 qv = ((const float2*)Q)[(size_t)n * 64 + d];
    float qf = qv.x, qs = qv.y;
    float wf = Wf[128 * 64 + d];
    float ws = Ws[128 * 64 + d];

    size_t idx = (size_t)n * 64 + d;
    float hres = h[idx];

    int rb = rowptr[n], re = rowptr[n + 1];
    float agg = 0.f;
#pragma unroll 8
    for (int p = rb; p < re; ++p) {
        int2 se = e_se[p];         // wave-uniform 8B load
        int s = se.x;
        float ea = __int_as_float(se.y);
        unsigned int pv = P[(size_t)s * 64 + d];   // gathered dword (256B/wave)
        float pf = __uint_as_float(pv << 16);
        float psv = __uint_as_float(pv & 0xffff0000u);
        float xF = fmaf(ea, wf, qf + pf);
        float xS = fmaf(ea, ws, qs + psv);
        float sig = __builtin_amdgcn_rcpf(1.f + __expf(-xF));
        float t = __expf(-fabsf(xS));
        float sp = fmaxf(xS, 0.f) + __logf(1.f + t);
        agg = fmaf(sig, sp, agg);
    }

    float inv = 1.f / (float)max(re - rb, 1);
    hout[idx] = fmaxf(hres + agg * inv, 0.f);
}

// ---------------------------------------------------------------------------
// Graph segment starts: bm sorted; gstart[b] = first node of graph b.
// ---------------------------------------------------------------------------
__global__ __launch_bounds__(256) void gstart_kernel(
    const int* __restrict__ bm, int* __restrict__ gstart, int N)
{
    int i = blockIdx.x * blockDim.x + threadIdx.x;
    if (i >= N) return;
    int b = bm[i];
    int prev = (i == 0) ? -1 : bm[i - 1];
    for (int g = prev + 1; g <= b; ++g) gstart[g] = i;
    if (i == N - 1)
        for (int g = b + 1; g <= GB; ++g) gstart[g] = N;
}

// ---------------------------------------------------------------------------
// Segmented mean pool: one block per graph, no atomics.
// ---------------------------------------------------------------------------
__global__ __launch_bounds__(256) void pool_seg_kernel(
    const float* __restrict__ h, const int* __restrict__ gstart,
    float* __restrict__ g)
{
    int b = blockIdx.x;
    int s = gstart[b], e = gstart[b + 1];
    int d = threadIdx.x & 63;
    int w = threadIdx.x >> 6;
    float acc = 0.f;
    for (int n = s + w; n < e; n += 4)
        acc += h[(size_t)n * 64 + d];
    __shared__ float lds[256];
    lds[threadIdx.x] = acc;
    __syncthreads();
    if (w == 0) {
        acc = lds[d] + lds[64 + d] + lds[128 + d] + lds[192 + d];
        g[b * 64 + d] = acc / fmaxf((float)(e - s), 1.f);
    }
}

// ---------------------------------------------------------------------------
// Fused post-MLP (3 relu layers) + final dot + bias. One wave per graph.
// ---------------------------------------------------------------------------
__global__ __launch_bounds__(256) void postmlp_kernel(
    const float* __restrict__ g,
    const float* __restrict__ W0, const float* __restrict__ b0,
    const float* __restrict__ W1, const float* __restrict__ b1,
    const float* __restrict__ W2, const float* __restrict__ b2,
    const float* __restrict__ Wfin, const float* __restrict__ bfin,
    float* __restrict__ out)
{
    int b = blockIdx.x * 4 + (threadIdx.x >> 6);   // 32 blocks x 4 waves = 128
    int d = threadIdx.x & 63;
    float h = g[(size_t)b * 64 + d];

    float acc = b0[d];
#pragma unroll
    for (int k = 0; k < 64; ++k)
        acc = fmaf(__shfl(h, k, 64), W0[k * 64 + d], acc);
    h = fmaxf(acc, 0.f);

    acc = b1[d];
#pragma unroll
    for (int k = 0; k < 64; ++k)
        acc = fmaf(__shfl(h, k, 64), W1[k * 64 + d], acc);
    h = fmaxf(acc, 0.f);

    acc = b2[d];
#pragma unroll
    for (int k = 0; k < 64; ++k)
        acc = fmaf(__shfl(h, k, 64), W2[k * 64 + d], acc);
    h = fmaxf(acc, 0.f);

    float v = h * Wfin[d];
#pragma unroll
    for (int off = 32; off >= 1; off >>= 1)
        v += __shfl_xor(v, off, 64);
    if (d == 0) out[b] = v + bfin[0];
}

extern "C" void kernel_launch(void* const* d_in, const int* in_sizes, int n_in,
                              void* d_out, int out_size, void* d_ws, size_t ws_size,
                              hipStream_t stream)
{
    const float* X      = (const float*)d_in[0];
    const int*   eidx   = (const int*)d_in[1];
    const float* ea     = (const float*)d_in[3];
    const int*   bm     = (const int*)d_in[4];
    const float* pre_W0 = (const float*)d_in[5];
    const float* pre_b0 = (const float*)d_in[6];
    const float* pre_W1 = (const float*)d_in[7];
    const float* pre_b1 = (const float*)d_in[8];
    const float* pre_W2 = (const float*)d_in[9];
    const float* pre_b2 = (const float*)d_in[10];
    const float* cg_Wf  = (const float*)d_in[11];
    const float* cg_bf  = (const float*)d_in[12];
    const float* cg_Ws  = (const float*)d_in[13];
    const float* cg_bs  = (const float*)d_in[14];
    const float* post_W0 = (const float*)d_in[15];
    const float* post_b0 = (const float*)d_in[16];
    const float* post_W1 = (const float*)d_in[17];
    const float* post_b1 = (const float*)d_in[18];
    const float* post_W2 = (const float*)d_in[19];
    const float* post_b2 = (const float*)d_in[20];
    const float* post_Wf = (const float*)d_in[21];
    const float* post_bf = (const float*)d_in[22];

    const int* src = eidx;
    const int* dst = eidx + GE;

    // ---- workspace carve-up ----
    const size_t N64 = (size_t)GN * 64;
    float* hA    = (float*)d_ws;            // N*64
    float* hB    = hA + N64;                // N*64
    unsigned int* P = (unsigned int*)(hB + N64);  // N*64 packed bf16x2
    int* deg_i   = (int*)(P + N64);         // N
    int* iscan   = deg_i + GN;              // N
    int* bsum    = iscan + GN;              // 128
    int* boff    = bsum + 128;              // 128
    int* rowptr  = boff + 128;              // N+2 (padded so e_se is 8B-aligned)
    int* cursor  = rowptr + GN + 2;         // N
    int2* e_se   = (int2*)(cursor + GN);    // E int2 (8B-aligned)
    int* gstart  = (int*)(e_se + GE);       // B+1
    float* g0    = (float*)(gstart + GB + 1); // B*64 (8192 floats, keeps 8B align)
    float* Q     = g0 + (size_t)GB * 64;    // N*128 fp32 (qf,qs) pairs

    const int TPB = 256;
    int gridE  = (GE + TPB - 1) / TPB;
    int gridN  = (GN + TPB - 1) / TPB;         // 391 (lane=node grid)
    int gridP  = (GN + 127) / 128;             // 782 (4 waves x 32 nodes per block)
    int gridND = ((GN * 64) + TPB - 1) / TPB;  // 25000 (edge grid)
    int scanBlocks = (GN + 1023) / 1024;       // 98

    // per-layer weight pointers
    const float* Wf0 = cg_Wf;
    const float* Ws0 = cg_Ws;
    const float* Wf1 = cg_Wf + (size_t)1 * GZ * GD;
    const float* Ws1 = cg_Ws + (size_t)1 * GZ * GD;
    const float* Wf2 = cg_Wf + (size_t)2 * GZ * GD;
    const float* Ws2 = cg_Ws + (size_t)2 * GZ * GD;

    // fused pre-MLP (weights-in-VGPR, hB as ping-pong scratch) + P0 + Q0
    premlp_kernel<<<gridP, TPB, 0, stream>>>(
        X, pre_W0, pre_b0, pre_W1, pre_b1, pre_W2, pre_b2,
        Wf0, Ws0, Wf0 + 64 * 64, Ws0 + 64 * 64, cg_bf, cg_bs,
        hA, hB, P, Q, GN);

    // degree + CSR build
    hipMemsetAsync(deg_i, 0, GN * sizeof(int), stream);
    deg_kernel<<<gridE, TPB, 0, stream>>>(dst, deg_i, GE);
    scanA_kernel<<<scanBlocks, 1024, 0, stream>>>(deg_i, iscan, bsum, GN);
    scanB_kernel<<<1, 128, 0, stream>>>(bsum, boff, scanBlocks);
    scanC_kernel<<<gridN, TPB, 0, stream>>>(iscan, boff, deg_i, rowptr, cursor, GN);
    escatter_kernel<<<gridE, TPB, 0, stream>>>(src, dst, ea, cursor, e_se, GE);

    // graph segment starts (bm sorted)
    gstart_kernel<<<gridN, TPB, 0, stream>>>(bm, gstart, GN);

    // CGConv layers: lean edge pass + fused P/Q projection for next layer
    edge_kernel<<<gridND, TPB, 0, stream>>>(
        hA, rowptr, e_se, P, Q, Wf0, Ws0, hB);
    pjq_kernel<<<gridP, TPB, 0, stream>>>(
        hB, Wf1, Ws1, cg_bf + GD, cg_bs + GD, P, Q, GN);
    edge_kernel<<<gridND, TPB, 0, stream>>>(
        hB, rowptr, e_se, P, Q, Wf1, Ws1, hA);
    pjq_kernel<<<gridP, TPB, 0, stream>>>(
        hA, Wf2, Ws2, cg_bf + 2 * GD, cg_bs + 2 * GD, P, Q, GN);
    edge_kernel<<<gridND, TPB, 0, stream>>>(
        hA, rowptr, e_se, P, Q, Wf2, Ws2, hB);

    // segmented mean pool (no atomics)
    pool_seg_kernel<<<GB, TPB, 0, stream>>>(hB, gstart, g0);

    // fused post-MLP + final projection
    postmlp_kernel<<<GB / 4, TPB, 0, stream>>>(
        g0, post_W0, post_b0, post_W1, post_b1, post_W2, post_b2,
        post_Wf, post_bf, (float*)d_out);
}

// Round 7
// 1300.677 us; speedup vs baseline: 2.8905x; 1.4540x over previous
//
#include <hip/hip_runtime.h>
#include <hip/hip_bf16.h>
#include <math.h>

// Problem constants (fixed by the reference)
#define GN 100000   // nodes
#define GE 1200000  // edges
#define GB 128      // graphs
#define GF 92       // raw features
#define GD 64       // hidden dim
#define GL 3        // CGConv layers
#define GZ 129      // 2*D+1

#define CH 32       // nodes per wave in dense kernels

// round-to-nearest-even fp32 -> bf16 (returned in low 16 bits)
__device__ __forceinline__ unsigned int f2bf_rne(float x)
{
    unsigned int u = __float_as_uint(x);
    u += 0x7fffu + ((u >> 16) & 1u);
    return u >> 16;
}

// 64-K dot: h row via wave-uniform float4 VMEM loads, weights per-lane in VGPRs.
__device__ __forceinline__ float dot64(const float4* __restrict__ hr,
                                       const float (&w)[64], float a)
{
#pragma unroll
    for (int c = 0; c < 16; ++c) {
        float4 v = hr[c];
        a = fmaf(v.x, w[4 * c + 0], a);
        a = fmaf(v.y, w[4 * c + 1], a);
        a = fmaf(v.z, w[4 * c + 2], a);
        a = fmaf(v.w, w[4 * c + 3], a);
    }
    return a;
}

// dual-gate 64-K dot (F and S share the h row loads)
__device__ __forceinline__ void dot64x2(const float4* __restrict__ hr,
                                        const float (&wf)[64], const float (&ws)[64],
                                        float& f, float& s)
{
#pragma unroll
    for (int c = 0; c < 16; ++c) {
        float4 v = hr[c];
        f = fmaf(v.x, wf[4 * c + 0], f);
        f = fmaf(v.y, wf[4 * c + 1], f);
        f = fmaf(v.z, wf[4 * c + 2], f);
        f = fmaf(v.w, wf[4 * c + 3], f);
        s = fmaf(v.x, ws[4 * c + 0], s);
        s = fmaf(v.y, ws[4 * c + 1], s);
        s = fmaf(v.z, ws[4 * c + 2], s);
        s = fmaf(v.w, ws[4 * c + 3], s);
    }
}

// ---------------------------------------------------------------------------
// Fused pre-MLP (3 layers) + P0 + Q0.
// Theory (R15): weights-in-VGPR / lane=column frees the LDS pipe that pinned
// R12-R14 at ~30% VALU. R15 failed on spill (84-reg cap); R16 failed on
// residual spill at 128 + F/S-split write amplification (414MB writes).
// R17: __launch_bounds__(256,1) -> 256-reg cap (no spill: L0 ~125 regs,
// dual-gate ~210); P/Q dual-gate phases process ONE node per iter to bound
// live float4s; outputs written once (packed dword / float2) -> no
// amplification. Zero LDS, zero syncthreads. FMA order (k ascending, x..w)
// identical to R12-R16 -> bitwise-same results.
// ---------------------------------------------------------------------------
__global__ __launch_bounds__(256, 1) void premlp_kernel(
    const float* __restrict__ X,
    const float* __restrict__ W0, const float* __restrict__ b0,
    const float* __restrict__ W1, const float* __restrict__ b1,
    const float* __restrict__ W2, const float* __restrict__ b2,
    const float* __restrict__ WfD, const float* __restrict__ WsD,   // rows 0..63
    const float* __restrict__ WfS, const float* __restrict__ WsS,   // rows 64..127
    const float* __restrict__ bf, const float* __restrict__ bs,
    float* __restrict__ ha, float* __restrict__ hb,
    unsigned int* __restrict__ Pout, float* __restrict__ Qout, int N)
{
    const int lane = threadIdx.x & 63;
    const int base = (blockIdx.x * 4 + (threadIdx.x >> 6)) * CH;
    if (base >= N) return;

    // ---- L0: X (K=92) @ W0 + b0, relu -> ha ----
    {
        float w[92];
#pragma unroll
        for (int k = 0; k < 92; ++k) w[k] = W0[k * 64 + lane];
        const float bias = b0[lane];
        for (int r = 0; r < CH; r += 2) {
            const int n0 = base + r, n1 = base + r + 1;
            const float4* __restrict__ x0 =
                (const float4*)(X + (size_t)((n0 < N) ? n0 : N - 1) * GF);
            const float4* __restrict__ x1 =
                (const float4*)(X + (size_t)((n1 < N) ? n1 : N - 1) * GF);
            float a0 = bias, a1 = bias;
#pragma unroll
            for (int c = 0; c < 23; ++c) {
                float4 v0 = x0[c], v1 = x1[c];
                a0 = fmaf(v0.x, w[4 * c + 0], a0);
                a0 = fmaf(v0.y, w[4 * c + 1], a0);
                a0 = fmaf(v0.z, w[4 * c + 2], a0);
                a0 = fmaf(v0.w, w[4 * c + 3], a0);
                a1 = fmaf(v1.x, w[4 * c + 0], a1);
                a1 = fmaf(v1.y, w[4 * c + 1], a1);
                a1 = fmaf(v1.z, w[4 * c + 2], a1);
                a1 = fmaf(v1.w, w[4 * c + 3], a1);
            }
            if (n0 < N) ha[(size_t)n0 * 64 + lane] = fmaxf(a0, 0.f);
            if (n1 < N) ha[(size_t)n1 * 64 + lane] = fmaxf(a1, 0.f);
        }
    }
    asm volatile("s_waitcnt vmcnt(0)" ::: "memory");

    // ---- L1: ha @ W1 + b1, relu -> hb ----
    {
        float w[64];
#pragma unroll
        for (int k = 0; k < 64; ++k) w[k] = W1[k * 64 + lane];
        const float bias = b1[lane];
        for (int r = 0; r < CH; r += 2) {
            const int n0 = base + r, n1 = base + r + 1;
            const float4* __restrict__ h0 =
                (const float4*)(ha + (size_t)((n0 < N) ? n0 : N - 1) * 64);
            const float4* __restrict__ h1 =
                (const float4*)(ha + (size_t)((n1 < N) ? n1 : N - 1) * 64);
            float a0 = dot64(h0, w, bias);
            float a1 = dot64(h1, w, bias);
            if (n0 < N) hb[(size_t)n0 * 64 + lane] = fmaxf(a0, 0.f);
            if (n1 < N) hb[(size_t)n1 * 64 + lane] = fmaxf(a1, 0.f);
        }
    }
    asm volatile("s_waitcnt vmcnt(0)" ::: "memory");

    // ---- L2: hb @ W2 + b2, relu -> ha (final h) ----
    {
        float w[64];
#pragma unroll
        for (int k = 0; k < 64; ++k) w[k] = W2[k * 64 + lane];
        const float bias = b2[lane];
        for (int r = 0; r < CH; r += 2) {
            const int n0 = base + r, n1 = base + r + 1;
            const float4* __restrict__ h0 =
                (const float4*)(hb + (size_t)((n0 < N) ? n0 : N - 1) * 64);
            const float4* __restrict__ h1 =
                (const float4*)(hb + (size_t)((n1 < N) ? n1 : N - 1) * 64);
            float a0 = dot64(h0, w, bias);
            float a1 = dot64(h1, w, bias);
            if (n0 < N) ha[(size_t)n0 * 64 + lane] = fmaxf(a0, 0.f);
            if (n1 < N) ha[(size_t)n1 * 64 + lane] = fmaxf(a1, 0.f);
        }
    }
    asm volatile("s_waitcnt vmcnt(0)" ::: "memory");

    // ---- P0: src-half gates (WfS/WsS) dual-gate, packed bf16 -> Pout ----
    {
        float wf[64], ws[64];
#pragma unroll
        for (int k = 0; k < 64; ++k) {
            wf[k] = WfS[k * 64 + lane];
            ws[k] = WsS[k * 64 + lane];
        }
        for (int r = 0; r < CH; ++r) {
            const int n0 = base + r;
            const float4* __restrict__ h0 =
                (const float4*)(ha + (size_t)((n0 < N) ? n0 : N - 1) * 64);
            float f0 = 0.f, s0 = 0.f;
            dot64x2(h0, wf, ws, f0, s0);
            if (n0 < N) Pout[(size_t)n0 * 64 + lane] = f2bf_rne(f0) | (f2bf_rne(s0) << 16);
        }
    }

    // ---- Q0: dst-half gates (WfD/WsD) + bias, fp32 (qf,qs) -> Qout ----
    {
        float wf[64], ws[64];
#pragma unroll
        for (int k = 0; k < 64; ++k) {
            wf[k] = WfD[k * 64 + lane];
            ws[k] = WsD[k * 64 + lane];
        }
        const float bfj = bf[lane], bsj = bs[lane];
        for (int r = 0; r < CH; ++r) {
            const int n0 = base + r;
            const float4* __restrict__ h0 =
                (const float4*)(ha + (size_t)((n0 < N) ? n0 : N - 1) * 64);
            float f0 = bfj, s0 = bsj;
            dot64x2(h0, wf, ws, f0, s0);
            if (n0 < N) ((float2*)Qout)[(size_t)n0 * 64 + lane] = make_float2(f0, s0);
        }
    }
}

// ---------------------------------------------------------------------------
// Gate projections for one CGConv layer: P (src half, packed bf16) and
// Q (dst half + bias, fp32 (qf,qs) pairs).
// R17: weights-in-VGPR dual-gate, one node per iteration, 256-reg cap.
// Input h read-only -> no hazards, no waits.
// ---------------------------------------------------------------------------
__global__ __launch_bounds__(256, 1) void pjq_kernel(
    const float* __restrict__ h,
    const float* __restrict__ Wf, const float* __restrict__ Ws,
    const float* __restrict__ bfv, const float* __restrict__ bsv,
    unsigned int* __restrict__ P, float* __restrict__ Q, int N)
{
    const int lane = threadIdx.x & 63;
    const int base = (blockIdx.x * 4 + (threadIdx.x >> 6)) * CH;
    if (base >= N) return;

    // ---- P: rows 64..127, dual-gate ----
    {
        float wf[64], ws[64];
#pragma unroll
        for (int k = 0; k < 64; ++k) {
            wf[k] = Wf[(64 + k) * 64 + lane];
            ws[k] = Ws[(64 + k) * 64 + lane];
        }
        for (int r = 0; r < CH; ++r) {
            const int n0 = base + r;
            const float4* __restrict__ h0 =
                (const float4*)(h + (size_t)((n0 < N) ? n0 : N - 1) * 64);
            float f0 = 0.f, s0 = 0.f;
            dot64x2(h0, wf, ws, f0, s0);
            if (n0 < N) P[(size_t)n0 * 64 + lane] = f2bf_rne(f0) | (f2bf_rne(s0) << 16);
        }
    }

    // ---- Q: rows 0..63 + bias, dual-gate ----
    {
        float wf[64], ws[64];
#pragma unroll
        for (int k = 0; k < 64; ++k) {
            wf[k] = Wf[k * 64 + lane];
            ws[k] = Ws[k * 64 + lane];
        }
        const float bfj = bfv[lane], bsj = bsv[lane];
        for (int r = 0; r < CH; ++r) {
            const int n0 = base + r;
            const float4* __restrict__ h0 =
                (const float4*)(h + (size_t)((n0 < N) ? n0 : N - 1) * 64);
            float f0 = bfj, s0 = bsj;
            dot64x2(h0, wf, ws, f0, s0);
            if (n0 < N) ((float2*)Q)[(size_t)n0 * 64 + lane] = make_float2(f0, s0);
        }
    }
}

// ---------------------------------------------------------------------------
// In-degree histogram (int)
// ---------------------------------------------------------------------------
__global__ __launch_bounds__(256) void deg_kernel(
    const int* __restrict__ dst, int* __restrict__ deg, int E)
{
    int e = blockIdx.x * blockDim.x + threadIdx.x;
    if (e < E) atomicAdd(&deg[dst[e]], 1);
}

// ---------------------------------------------------------------------------
// Three-phase exclusive scan over deg -> rowptr, cursor
// ---------------------------------------------------------------------------
__global__ __launch_bounds__(1024) void scanA_kernel(
    const int* __restrict__ deg, int* __restrict__ iscan,
    int* __restrict__ bsum, int N)
{
    __shared__ int lds[1024];
    int tid = threadIdx.x;
    int gid = blockIdx.x * 1024 + tid;
    int v = (gid < N) ? deg[gid] : 0;
    lds[tid] = v; __syncthreads();
    for (int off = 1; off < 1024; off <<= 1) {
        int t = (tid >= off) ? lds[tid - off] : 0;
        __syncthreads();
        lds[tid] += t;
        __syncthreads();
    }
    if (gid < N) iscan[gid] = lds[tid];
    if (tid == 1023) bsum[blockIdx.x] = lds[1023];
}

__global__ __launch_bounds__(128) void scanB_kernel(
    const int* __restrict__ bsum, int* __restrict__ boff, int nb)
{
    __shared__ int lds[128];
    int t = threadIdx.x;
    int v = (t < nb) ? bsum[t] : 0;
    lds[t] = v; __syncthreads();
    for (int off = 1; off < 128; off <<= 1) {
        int u = (t >= off) ? lds[t - off] : 0;
        __syncthreads();
        lds[t] += u;
        __syncthreads();
    }
    if (t < nb) boff[t] = lds[t] - v;  // exclusive
}

__global__ __launch_bounds__(256) void scanC_kernel(
    const int* __restrict__ iscan, const int* __restrict__ boff,
    const int* __restrict__ deg,
    int* __restrict__ rowptr, int* __restrict__ cursor, int N)
{
    int i = blockIdx.x * blockDim.x + threadIdx.x;
    if (i >= N) return;
    int incl = iscan[i] + boff[i >> 10];
    rowptr[i + 1] = incl;
    cursor[i] = incl - deg[i];
    if (i == 0) rowptr[0] = 0;
}

// ---------------------------------------------------------------------------
// Edge scatter into CSR order, packed (src, ea) int2
// ---------------------------------------------------------------------------
__global__ __launch_bounds__(256) void escatter_kernel(
    const int* __restrict__ src, const int* __restrict__ dst,
    const float* __restrict__ ea, int* __restrict__ cursor,
    int2* __restrict__ e_se, int E)
{
    int e = blockIdx.x * blockDim.x + threadIdx.x;
    if (e >= E) return;
    int pos = atomicAdd(&cursor[dst[e]], 1);
    e_se[pos] = make_int2(src[e], __float_as_int(ea[e]));
}

// ---------------------------------------------------------------------------
// CGConv edge pass. One wave per node, lane = dim. Q precomputed (R12).
// ---------------------------------------------------------------------------
__global__ __launch_bounds__(256) void edge_kernel(
    const float* __restrict__ h, const int* __restrict__ rowptr,
    const int2* __restrict__ e_se,
    const unsigned int* __restrict__ P,
    const float* __restrict__ Q,
    const float* __restrict__ Wf, const float* __restrict__ Ws,
    float* __restrict__ hout)
{
    int n = blockIdx.x * 4 + (threadIdx.x >> 6);   // grid exactly covers GN
    int d = threadIdx.x & 63;

    const float2 qv = ((const float2*)Q)[(size_t)n * 64 + d];
    float qf = qv.x, qs = qv.y;
    float wf = Wf[128 * 64 + d];
    float ws = Ws[128 * 64 + d];

    size_t idx = (size_t)n * 64 + d;
    float hres = h[idx];

    int rb = rowptr[n], re = rowptr[n + 1];
    float agg = 0.f;
#pragma unroll 8
    for (int p = rb; p < re; ++p) {
        int2 se = e_se[p];         // wave-uniform 8B load
        int s = se.x;
        float ea = __int_as_float(se.y);
        unsigned int pv = P[(size_t)s * 64 + d];   // gathered dword (256B/wave)
        float pf = __uint_as_float(pv << 16);
        float psv = __uint_as_float(pv & 0xffff0000u);
        float xF = fmaf(ea, wf, qf + pf);
        float xS = fmaf(ea, ws, qs + psv);
        float sig = __builtin_amdgcn_rcpf(1.f + __expf(-xF));
        float t = __expf(-fabsf(xS));
        float sp = fmaxf(xS, 0.f) + __logf(1.f + t);
        agg = fmaf(sig, sp, agg);
    }

    float inv = 1.f / (float)max(re - rb, 1);
    hout[idx] = fmaxf(hres + agg * inv, 0.f);
}

// ---------------------------------------------------------------------------
// Graph segment starts: bm sorted; gstart[b] = first node of graph b.
// ---------------------------------------------------------------------------
__global__ __launch_bounds__(256) void gstart_kernel(
    const int* __restrict__ bm, int* __restrict__ gstart, int N)
{
    int i = blockIdx.x * blockDim.x + threadIdx.x;
    if (i >= N) return;
    int b = bm[i];
    int prev = (i == 0) ? -1 : bm[i - 1];
    for (int g = prev + 1; g <= b; ++g) gstart[g] = i;
    if (i == N - 1)
        for (int g = b + 1; g <= GB; ++g) gstart[g] = N;
}

// ---------------------------------------------------------------------------
// Segmented mean pool: one block per graph, no atomics.
// ---------------------------------------------------------------------------
__global__ __launch_bounds__(256) void pool_seg_kernel(
    const float* __restrict__ h, const int* __restrict__ gstart,
    float* __restrict__ g)
{
    int b = blockIdx.x;
    int s = gstart[b], e = gstart[b + 1];
    int d = threadIdx.x & 63;
    int w = threadIdx.x >> 6;
    float acc = 0.f;
    for (int n = s + w; n < e; n += 4)
        acc += h[(size_t)n * 64 + d];
    __shared__ float lds[256];
    lds[threadIdx.x] = acc;
    __syncthreads();
    if (w == 0) {
        acc = lds[d] + lds[64 + d] + lds[128 + d] + lds[192 + d];
        g[b * 64 + d] = acc / fmaxf((float)(e - s), 1.f);
    }
}

// ---------------------------------------------------------------------------
// Fused post-MLP (3 relu layers) + final dot + bias. One wave per graph.
// ---------------------------------------------------------------------------
__global__ __launch_bounds__(256) void postmlp_kernel(
    const float* __restrict__ g,
    const float* __restrict__ W0, const float* __restrict__ b0,
    const float* __restrict__ W1, const float* __restrict__ b1,
    const float* __restrict__ W2, const float* __restrict__ b2,
    const float* __restrict__ Wfin, const float* __restrict__ bfin,
    float* __restrict__ out)
{
    int b = blockIdx.x * 4 + (threadIdx.x >> 6);   // 32 blocks x 4 waves = 128
    int d = threadIdx.x & 63;
    float h = g[(size_t)b * 64 + d];

    float acc = b0[d];
#pragma unroll
    for (int k = 0; k < 64; ++k)
        acc = fmaf(__shfl(h, k, 64), W0[k * 64 + d], acc);
    h = fmaxf(acc, 0.f);

    acc = b1[d];
#pragma unroll
    for (int k = 0; k < 64; ++k)
        acc = fmaf(__shfl(h, k, 64), W1[k * 64 + d], acc);
    h = fmaxf(acc, 0.f);

    acc = b2[d];
#pragma unroll
    for (int k = 0; k < 64; ++k)
        acc = fmaf(__shfl(h, k, 64), W2[k * 64 + d], acc);
    h = fmaxf(acc, 0.f);

    float v = h * Wfin[d];
#pragma unroll
    for (int off = 32; off >= 1; off >>= 1)
        v += __shfl_xor(v, off, 64);
    if (d == 0) out[b] = v + bfin[0];
}

extern "C" void kernel_launch(void* const* d_in, const int* in_sizes, int n_in,
                              void* d_out, int out_size, void* d_ws, size_t ws_size,
                              hipStream_t stream)
{
    const float* X      = (const float*)d_in[0];
    const int*   eidx   = (const int*)d_in[1];
    const float* ea     = (const float*)d_in[3];
    const int*   bm     = (const int*)d_in[4];
    const float* pre_W0 = (const float*)d_in[5];
    const float* pre_b0 = (const float*)d_in[6];
    const float* pre_W1 = (const float*)d_in[7];
    const float* pre_b1 = (const float*)d_in[8];
    const float* pre_W2 = (const float*)d_in[9];
    const float* pre_b2 = (const float*)d_in[10];
    const float* cg_Wf  = (const float*)d_in[11];
    const float* cg_bf  = (const float*)d_in[12];
    const float* cg_Ws  = (const float*)d_in[13];
    const float* cg_bs  = (const float*)d_in[14];
    const float* post_W0 = (const float*)d_in[15];
    const float* post_b0 = (const float*)d_in[16];
    const float* post_W1 = (const float*)d_in[17];
    const float* post_b1 = (const float*)d_in[18];
    const float* post_W2 = (const float*)d_in[19];
    const float* post_b2 = (const float*)d_in[20];
    const float* post_Wf = (const float*)d_in[21];
    const float* post_bf = (const float*)d_in[22];

    const int* src = eidx;
    const int* dst = eidx + GE;

    // ---- workspace carve-up ----
    const size_t N64 = (size_t)GN * 64;
    float* hA    = (float*)d_ws;            // N*64
    float* hB    = hA + N64;                // N*64
    unsigned int* P = (unsigned int*)(hB + N64);  // N*64 packed bf16x2
    int* deg_i   = (int*)(P + N64);         // N
    int* iscan   = deg_i + GN;              // N
    int* bsum    = iscan + GN;              // 128
    int* boff    = bsum + 128;              // 128
    int* rowptr  = boff + 128;              // N+2 (padded so e_se is 8B-aligned)
    int* cursor  = rowptr + GN + 2;         // N
    int2* e_se   = (int2*)(cursor + GN);    // E int2 (8B-aligned)
    int* gstart  = (int*)(e_se + GE);       // B+1
    float* g0    = (float*)(gstart + GB + 1); // B*64 (8192 floats, keeps 8B align)
    float* Q     = g0 + (size_t)GB * 64;    // N*128 fp32 (qf,qs) pairs

    const int TPB = 256;
    int gridE  = (GE + TPB - 1) / TPB;
    int gridN  = (GN + TPB - 1) / TPB;         // 391 (lane=node grid)
    int gridP  = (GN + 127) / 128;             // 782 (4 waves x 32 nodes per block)
    int gridND = ((GN * 64) + TPB - 1) / TPB;  // 25000 (edge grid)
    int scanBlocks = (GN + 1023) / 1024;       // 98

    // per-layer weight pointers
    const float* Wf0 = cg_Wf;
    const float* Ws0 = cg_Ws;
    const float* Wf1 = cg_Wf + (size_t)1 * GZ * GD;
    const float* Ws1 = cg_Ws + (size_t)1 * GZ * GD;
    const float* Wf2 = cg_Wf + (size_t)2 * GZ * GD;
    const float* Ws2 = cg_Ws + (size_t)2 * GZ * GD;

    // fused pre-MLP (weights-in-VGPR, hB as ping-pong scratch) + P0 + Q0
    premlp_kernel<<<gridP, TPB, 0, stream>>>(
        X, pre_W0, pre_b0, pre_W1, pre_b1, pre_W2, pre_b2,
        Wf0, Ws0, Wf0 + 64 * 64, Ws0 + 64 * 64, cg_bf, cg_bs,
        hA, hB, P, Q, GN);

    // degree + CSR build
    hipMemsetAsync(deg_i, 0, GN * sizeof(int), stream);
    deg_kernel<<<gridE, TPB, 0, stream>>>(dst, deg_i, GE);
    scanA_kernel<<<scanBlocks, 1024, 0, stream>>>(deg_i, iscan, bsum, GN);
    scanB_kernel<<<1, 128, 0, stream>>>(bsum, boff, scanBlocks);
    scanC_kernel<<<gridN, TPB, 0, stream>>>(iscan, boff, deg_i, rowptr, cursor, GN);
    escatter_kernel<<<gridE, TPB, 0, stream>>>(src, dst, ea, cursor, e_se, GE);

    // graph segment starts (bm sorted)
    gstart_kernel<<<gridN, TPB, 0, stream>>>(bm, gstart, GN);

    // CGConv layers: lean edge pass + fused P/Q projection for next layer
    edge_kernel<<<gridND, TPB, 0, stream>>>(
        hA, rowptr, e_se, P, Q, Wf0, Ws0, hB);
    pjq_kernel<<<gridP, TPB, 0, stream>>>(
        hB, Wf1, Ws1, cg_bf + GD, cg_bs + GD, P, Q, GN);
    edge_kernel<<<gridND, TPB, 0, stream>>>(
        hB, rowptr, e_se, P, Q, Wf1, Ws1, hA);
    pjq_kernel<<<gridP, TPB, 0, stream>>>(
        hA, Wf2, Ws2, cg_bf + 2 * GD, cg_bs + 2 * GD, P, Q, GN);
    edge_kernel<<<gridND, TPB, 0, stream>>>(
        hA, rowptr, e_se, P, Q, Wf2, Ws2, hB);

    // segmented mean pool (no atomics)
    pool_seg_kernel<<<GB, TPB, 0, stream>>>(hB, gstart, g0);

    // fused post-MLP + final projection
    postmlp_kernel<<<GB / 4, TPB, 0, stream>>>(
        g0, post_W0, post_b0, post_W1, post_b1, post_W2, post_b2,
        post_Wf, post_bf, (float*)d_out);
}

// Round 8
// 1037.921 us; speedup vs baseline: 3.6222x; 1.2532x over previous
//
#include <hip/hip_runtime.h>
#include <hip/hip_bf16.h>
#include <math.h>

// Problem constants (fixed by the reference)
#define GN 100000   // nodes
#define GE 1200000  // edges
#define GB 128      // graphs
#define GF 92       // raw features
#define GD 64       // hidden dim
#define GL 3        // CGConv layers
#define GZ 129      // 2*D+1

#define HS 65       // padded LDS h-tile stride (2-way bank alias = free)
#define EC 32       // edges per wave in edge-parallel pass

// round-to-nearest-even fp32 -> bf16 (returned in low 16 bits)
__device__ __forceinline__ unsigned int f2bf_rne(float x)
{
    unsigned int u = __float_as_uint(x);
    u += 0x7fffu + ((u >> 16) & 1u);
    return u >> 16;
}

// ---------------------------------------------------------------------------
// Fused pre-MLP (3 layers) + P0 + Q0.  (R14 form -- measured best: 166us.)
// 4-way column split (wave = 16-col slice), R=2 nodes/thread, weights + h
// tile staged in LDS. The R15-R17 weights-in-VGPR arc failed (spill, write
// amplification, VMEM-broadcast latency at 2 waves/SIMD) -- reverted.
// ---------------------------------------------------------------------------
__global__ __launch_bounds__(256, 2) void premlp_kernel(
    const float* __restrict__ X,
    const float* __restrict__ W0, const float* __restrict__ b0,
    const float* __restrict__ W1, const float* __restrict__ b1,
    const float* __restrict__ W2, const float* __restrict__ b2,
    const float* __restrict__ WfD, const float* __restrict__ WsD,   // rows 0..63
    const float* __restrict__ WfS, const float* __restrict__ WsS,   // rows 64..127
    const float* __restrict__ bf, const float* __restrict__ bs,
    float* __restrict__ hout, unsigned int* __restrict__ Pout,
    float* __restrict__ Qout, int N)
{
    __shared__ __align__(16) float Wl[5888];    // 23 KB weight stage (W0 needs it all)
    __shared__ float hl[128 * HS];              // 33.3 KB padded h tile (128 nodes)
    const int tid = threadIdx.x;
    const int lane = tid & 63;
    const int col0 = (tid >> 6) * 16;           // this wave's column slice
    const int base = blockIdx.x * 128;
    const int n0 = base + lane;
    const int n1 = base + 64 + lane;
    const int nn0 = (n0 < N) ? n0 : (N - 1);
    const int nn1 = (n1 < N) ? n1 : (N - 1);
    const bool act0 = (n0 < N), act1 = (n1 < N);

    float a0[16], a1[16], s0[16], s1[16];

    // ---- stage W0 (92x64 = 1472 float4) ----
    {
        const float4* __restrict__ s4 = (const float4*)W0;
        float4* __restrict__ d4 = (float4*)Wl;
        for (int i = tid; i < 1472; i += 256) d4[i] = s4[i];
    }
    __syncthreads();

    // ---- layer 0: K=92 ----
#pragma unroll
    for (int j = 0; j < 16; ++j) { a0[j] = b0[col0 + j]; a1[j] = a0[j]; }
    {
        const float4* __restrict__ r40 = (const float4*)(X + (size_t)nn0 * GF);
        const float4* __restrict__ r41 = (const float4*)(X + (size_t)nn1 * GF);
        for (int c = 0; c < 23; ++c) {
            float4 v0 = r40[c];
            float4 v1 = r41[c];
            const float* __restrict__ w = Wl + c * 256 + col0;
#pragma unroll
            for (int j = 0; j < 16; ++j) {
                float wa = w[j], wb = w[64 + j], wc = w[128 + j], wd = w[192 + j];
                a0[j] = fmaf(v0.x, wa, a0[j]);
                a0[j] = fmaf(v0.y, wb, a0[j]);
                a0[j] = fmaf(v0.z, wc, a0[j]);
                a0[j] = fmaf(v0.w, wd, a0[j]);
                a1[j] = fmaf(v1.x, wa, a1[j]);
                a1[j] = fmaf(v1.y, wb, a1[j]);
                a1[j] = fmaf(v1.z, wc, a1[j]);
                a1[j] = fmaf(v1.w, wd, a1[j]);
            }
        }
    }
    __syncthreads();    // all Wl reads done
#pragma unroll
    for (int j = 0; j < 16; ++j) {
        hl[lane * HS + col0 + j] = fmaxf(a0[j], 0.f);
        hl[(64 + lane) * HS + col0 + j] = fmaxf(a1[j], 0.f);
    }
    {
        const float4* __restrict__ s4 = (const float4*)W1;
        float4* __restrict__ d4 = (float4*)Wl;
        for (int i = tid; i < 1024; i += 256) d4[i] = s4[i];
    }
    __syncthreads();

    // ---- layer 1 ----
#pragma unroll
    for (int j = 0; j < 16; ++j) { a0[j] = b1[col0 + j]; a1[j] = a0[j]; }
    for (int c = 0; c < 16; ++c) {
        float h0 = hl[lane * HS + 4 * c + 0];
        float h1 = hl[lane * HS + 4 * c + 1];
        float h2 = hl[lane * HS + 4 * c + 2];
        float h3 = hl[lane * HS + 4 * c + 3];
        float g0 = hl[(64 + lane) * HS + 4 * c + 0];
        float g1 = hl[(64 + lane) * HS + 4 * c + 1];
        float g2 = hl[(64 + lane) * HS + 4 * c + 2];
        float g3 = hl[(64 + lane) * HS + 4 * c + 3];
        const float* __restrict__ w = Wl + c * 256 + col0;
#pragma unroll
        for (int j = 0; j < 16; ++j) {
            float wa = w[j], wb = w[64 + j], wc = w[128 + j], wd = w[192 + j];
            a0[j] = fmaf(h0, wa, a0[j]);
            a0[j] = fmaf(h1, wb, a0[j]);
            a0[j] = fmaf(h2, wc, a0[j]);
            a0[j] = fmaf(h3, wd, a0[j]);
            a1[j] = fmaf(g0, wa, a1[j]);
            a1[j] = fmaf(g1, wb, a1[j]);
            a1[j] = fmaf(g2, wc, a1[j]);
            a1[j] = fmaf(g3, wd, a1[j]);
        }
    }
    __syncthreads();
#pragma unroll
    for (int j = 0; j < 16; ++j) {
        hl[lane * HS + col0 + j] = fmaxf(a0[j], 0.f);
        hl[(64 + lane) * HS + col0 + j] = fmaxf(a1[j], 0.f);
    }
    {
        const float4* __restrict__ s4 = (const float4*)W2;
        float4* __restrict__ d4 = (float4*)Wl;
        for (int i = tid; i < 1024; i += 256) d4[i] = s4[i];
    }
    __syncthreads();

    // ---- layer 2 ----
#pragma unroll
    for (int j = 0; j < 16; ++j) { a0[j] = b2[col0 + j]; a1[j] = a0[j]; }
    for (int c = 0; c < 16; ++c) {
        float h0 = hl[lane * HS + 4 * c + 0];
        float h1 = hl[lane * HS + 4 * c + 1];
        float h2 = hl[lane * HS + 4 * c + 2];
        float h3 = hl[lane * HS + 4 * c + 3];
        float g0 = hl[(64 + lane) * HS + 4 * c + 0];
        float g1 = hl[(64 + lane) * HS + 4 * c + 1];
        float g2 = hl[(64 + lane) * HS + 4 * c + 2];
        float g3 = hl[(64 + lane) * HS + 4 * c + 3];
        const float* __restrict__ w = Wl + c * 256 + col0;
#pragma unroll
        for (int j = 0; j < 16; ++j) {
            float wa = w[j], wb = w[64 + j], wc = w[128 + j], wd = w[192 + j];
            a0[j] = fmaf(h0, wa, a0[j]);
            a0[j] = fmaf(h1, wb, a0[j]);
            a0[j] = fmaf(h2, wc, a0[j]);
            a0[j] = fmaf(h3, wd, a0[j]);
            a1[j] = fmaf(g0, wa, a1[j]);
            a1[j] = fmaf(g1, wb, a1[j]);
            a1[j] = fmaf(g2, wc, a1[j]);
            a1[j] = fmaf(g3, wd, a1[j]);
        }
    }
    __syncthreads();
#pragma unroll
    for (int j = 0; j < 16; ++j) {
        hl[lane * HS + col0 + j] = fmaxf(a0[j], 0.f);
        hl[(64 + lane) * HS + col0 + j] = fmaxf(a1[j], 0.f);
    }
    if (act0) {
        float4* __restrict__ op = (float4*)(hout + (size_t)n0 * 64 + col0);
#pragma unroll
        for (int q = 0; q < 4; ++q)
            op[q] = make_float4(fmaxf(a0[q * 4], 0.f), fmaxf(a0[q * 4 + 1], 0.f),
                                fmaxf(a0[q * 4 + 2], 0.f), fmaxf(a0[q * 4 + 3], 0.f));
    }
    if (act1) {
        float4* __restrict__ op = (float4*)(hout + (size_t)n1 * 64 + col0);
#pragma unroll
        for (int q = 0; q < 4; ++q)
            op[q] = make_float4(fmaxf(a1[q * 4], 0.f), fmaxf(a1[q * 4 + 1], 0.f),
                                fmaxf(a1[q * 4 + 2], 0.f), fmaxf(a1[q * 4 + 3], 0.f));
    }
    {
        const float4* __restrict__ s4 = (const float4*)WfS;
        float4* __restrict__ d4 = (float4*)Wl;
        for (int i = tid; i < 1024; i += 256) d4[i] = s4[i];
    }
    __syncthreads();

    // ---- P0-F ----
#pragma unroll
    for (int j = 0; j < 16; ++j) { a0[j] = 0.f; a1[j] = 0.f; }
    for (int c = 0; c < 16; ++c) {
        float h0 = hl[lane * HS + 4 * c + 0];
        float h1 = hl[lane * HS + 4 * c + 1];
        float h2 = hl[lane * HS + 4 * c + 2];
        float h3 = hl[lane * HS + 4 * c + 3];
        float g0 = hl[(64 + lane) * HS + 4 * c + 0];
        float g1 = hl[(64 + lane) * HS + 4 * c + 1];
        float g2 = hl[(64 + lane) * HS + 4 * c + 2];
        float g3 = hl[(64 + lane) * HS + 4 * c + 3];
        const float* __restrict__ w = Wl + c * 256 + col0;
#pragma unroll
        for (int j = 0; j < 16; ++j) {
            float wa = w[j], wb = w[64 + j], wc = w[128 + j], wd = w[192 + j];
            a0[j] = fmaf(h0, wa, a0[j]);
            a0[j] = fmaf(h1, wb, a0[j]);
            a0[j] = fmaf(h2, wc, a0[j]);
            a0[j] = fmaf(h3, wd, a0[j]);
            a1[j] = fmaf(g0, wa, a1[j]);
            a1[j] = fmaf(g1, wb, a1[j]);
            a1[j] = fmaf(g2, wc, a1[j]);
            a1[j] = fmaf(g3, wd, a1[j]);
        }
    }
    __syncthreads();
    {
        const float4* __restrict__ s4 = (const float4*)WsS;
        float4* __restrict__ d4 = (float4*)Wl;
        for (int i = tid; i < 1024; i += 256) d4[i] = s4[i];
    }
    __syncthreads();

    // ---- P0-S + store ----
#pragma unroll
    for (int j = 0; j < 16; ++j) { s0[j] = 0.f; s1[j] = 0.f; }
    for (int c = 0; c < 16; ++c) {
        float h0 = hl[lane * HS + 4 * c + 0];
        float h1 = hl[lane * HS + 4 * c + 1];
        float h2 = hl[lane * HS + 4 * c + 2];
        float h3 = hl[lane * HS + 4 * c + 3];
        float g0 = hl[(64 + lane) * HS + 4 * c + 0];
        float g1 = hl[(64 + lane) * HS + 4 * c + 1];
        float g2 = hl[(64 + lane) * HS + 4 * c + 2];
        float g3 = hl[(64 + lane) * HS + 4 * c + 3];
        const float* __restrict__ w = Wl + c * 256 + col0;
#pragma unroll
        for (int j = 0; j < 16; ++j) {
            float wa = w[j], wb = w[64 + j], wc = w[128 + j], wd = w[192 + j];
            s0[j] = fmaf(h0, wa, s0[j]);
            s0[j] = fmaf(h1, wb, s0[j]);
            s0[j] = fmaf(h2, wc, s0[j]);
            s0[j] = fmaf(h3, wd, s0[j]);
            s1[j] = fmaf(g0, wa, s1[j]);
            s1[j] = fmaf(g1, wb, s1[j]);
            s1[j] = fmaf(g2, wc, s1[j]);
            s1[j] = fmaf(g3, wd, s1[j]);
        }
    }
    if (act0) {
        uint4* __restrict__ pp = (uint4*)(Pout + (size_t)n0 * 64 + col0);
#pragma unroll
        for (int q = 0; q < 4; ++q) {
            uint4 pk;
            pk.x = f2bf_rne(a0[q * 4])     | (f2bf_rne(s0[q * 4]) << 16);
            pk.y = f2bf_rne(a0[q * 4 + 1]) | (f2bf_rne(s0[q * 4 + 1]) << 16);
            pk.z = f2bf_rne(a0[q * 4 + 2]) | (f2bf_rne(s0[q * 4 + 2]) << 16);
            pk.w = f2bf_rne(a0[q * 4 + 3]) | (f2bf_rne(s0[q * 4 + 3]) << 16);
            pp[q] = pk;
        }
    }
    if (act1) {
        uint4* __restrict__ pp = (uint4*)(Pout + (size_t)n1 * 64 + col0);
#pragma unroll
        for (int q = 0; q < 4; ++q) {
            uint4 pk;
            pk.x = f2bf_rne(a1[q * 4])     | (f2bf_rne(s1[q * 4]) << 16);
            pk.y = f2bf_rne(a1[q * 4 + 1]) | (f2bf_rne(s1[q * 4 + 1]) << 16);
            pk.z = f2bf_rne(a1[q * 4 + 2]) | (f2bf_rne(s1[q * 4 + 2]) << 16);
            pk.w = f2bf_rne(a1[q * 4 + 3]) | (f2bf_rne(s1[q * 4 + 3]) << 16);
            pp[q] = pk;
        }
    }
    __syncthreads();
    {
        const float4* __restrict__ s4 = (const float4*)WfD;
        float4* __restrict__ d4 = (float4*)Wl;
        for (int i = tid; i < 1024; i += 256) d4[i] = s4[i];
    }
    __syncthreads();

    // ---- Q0-F ----
#pragma unroll
    for (int j = 0; j < 16; ++j) { a0[j] = bf[col0 + j]; a1[j] = a0[j]; }
    for (int c = 0; c < 16; ++c) {
        float h0 = hl[lane * HS + 4 * c + 0];
        float h1 = hl[lane * HS + 4 * c + 1];
        float h2 = hl[lane * HS + 4 * c + 2];
        float h3 = hl[lane * HS + 4 * c + 3];
        float g0 = hl[(64 + lane) * HS + 4 * c + 0];
        float g1 = hl[(64 + lane) * HS + 4 * c + 1];
        float g2 = hl[(64 + lane) * HS + 4 * c + 2];
        float g3 = hl[(64 + lane) * HS + 4 * c + 3];
        const float* __restrict__ w = Wl + c * 256 + col0;
#pragma unroll
        for (int j = 0; j < 16; ++j) {
            float wa = w[j], wb = w[64 + j], wc = w[128 + j], wd = w[192 + j];
            a0[j] = fmaf(h0, wa, a0[j]);
            a0[j] = fmaf(h1, wb, a0[j]);
            a0[j] = fmaf(h2, wc, a0[j]);
            a0[j] = fmaf(h3, wd, a0[j]);
            a1[j] = fmaf(g0, wa, a1[j]);
            a1[j] = fmaf(g1, wb, a1[j]);
            a1[j] = fmaf(g2, wc, a1[j]);
            a1[j] = fmaf(g3, wd, a1[j]);
        }
    }
    __syncthreads();
    {
        const float4* __restrict__ s4 = (const float4*)WsD;
        float4* __restrict__ d4 = (float4*)Wl;
        for (int i = tid; i < 1024; i += 256) d4[i] = s4[i];
    }
    __syncthreads();

    // ---- Q0-S + store ----
#pragma unroll
    for (int j = 0; j < 16; ++j) { s0[j] = bs[col0 + j]; s1[j] = s0[j]; }
    for (int c = 0; c < 16; ++c) {
        float h0 = hl[lane * HS + 4 * c + 0];
        float h1 = hl[lane * HS + 4 * c + 1];
        float h2 = hl[lane * HS + 4 * c + 2];
        float h3 = hl[lane * HS + 4 * c + 3];
        float g0 = hl[(64 + lane) * HS + 4 * c + 0];
        float g1 = hl[(64 + lane) * HS + 4 * c + 1];
        float g2 = hl[(64 + lane) * HS + 4 * c + 2];
        float g3 = hl[(64 + lane) * HS + 4 * c + 3];
        const float* __restrict__ w = Wl + c * 256 + col0;
#pragma unroll
        for (int j = 0; j < 16; ++j) {
            float wa = w[j], wb = w[64 + j], wc = w[128 + j], wd = w[192 + j];
            s0[j] = fmaf(h0, wa, s0[j]);
            s0[j] = fmaf(h1, wb, s0[j]);
            s0[j] = fmaf(h2, wc, s0[j]);
            s0[j] = fmaf(h3, wd, s0[j]);
            s1[j] = fmaf(g0, wa, s1[j]);
            s1[j] = fmaf(g1, wb, s1[j]);
            s1[j] = fmaf(g2, wc, s1[j]);
            s1[j] = fmaf(g3, wd, s1[j]);
        }
    }
    if (act0) {
        float4* __restrict__ qp = (float4*)(Qout + (size_t)n0 * 128 + col0 * 2);
#pragma unroll
        for (int q = 0; q < 8; ++q)
            qp[q] = make_float4(a0[q * 2], s0[q * 2], a0[q * 2 + 1], s0[q * 2 + 1]);
    }
    if (act1) {
        float4* __restrict__ qp = (float4*)(Qout + (size_t)n1 * 128 + col0 * 2);
#pragma unroll
        for (int q = 0; q < 8; ++q)
            qp[q] = make_float4(a1[q * 2], s1[q * 2], a1[q * 2 + 1], s1[q * 2 + 1]);
    }
}

// ---------------------------------------------------------------------------
// Gate projections: P (src half, packed bf16) and Q (dst half + bias, fp32).
// R14 form (4-way column split, R=2 nodes/thread, LDS-staged).
// ---------------------------------------------------------------------------
__global__ __launch_bounds__(256, 3) void pjq_kernel(
    const float* __restrict__ h,
    const float* __restrict__ Wf, const float* __restrict__ Ws,
    const float* __restrict__ bfv, const float* __restrict__ bsv,
    unsigned int* __restrict__ P, float* __restrict__ Q, int N)
{
    __shared__ __align__(16) float Wl[4096];
    __shared__ float hl[128 * HS];
    const int tid = threadIdx.x;
    const int lane = tid & 63;
    const int col0 = (tid >> 6) * 16;
    const int base = blockIdx.x * 128;
    const int n0 = base + lane;
    const int n1 = base + 64 + lane;
    const bool act0 = (n0 < N), act1 = (n1 < N);

    float a0[16], a1[16], s0[16], s1[16];

    // stage h tile + WfS
    for (int q = tid; q < 2048; q += 256) {
        int r = q >> 4, c4 = q & 15;
        int rr = base + r; rr = (rr < N) ? rr : (N - 1);
        float4 v = ((const float4*)(h + (size_t)rr * 64))[c4];
        float* dp = hl + r * HS + c4 * 4;
        dp[0] = v.x; dp[1] = v.y; dp[2] = v.z; dp[3] = v.w;
    }
    {
        const float4* __restrict__ s4 = (const float4*)(Wf + 64 * 64);
        float4* __restrict__ d4 = (float4*)Wl;
        for (int i = tid; i < 1024; i += 256) d4[i] = s4[i];
    }
    __syncthreads();

    // ---- P-F ----
#pragma unroll
    for (int j = 0; j < 16; ++j) { a0[j] = 0.f; a1[j] = 0.f; }
    for (int c = 0; c < 16; ++c) {
        float h0 = hl[lane * HS + 4 * c + 0];
        float h1 = hl[lane * HS + 4 * c + 1];
        float h2 = hl[lane * HS + 4 * c + 2];
        float h3 = hl[lane * HS + 4 * c + 3];
        float g0 = hl[(64 + lane) * HS + 4 * c + 0];
        float g1 = hl[(64 + lane) * HS + 4 * c + 1];
        float g2 = hl[(64 + lane) * HS + 4 * c + 2];
        float g3 = hl[(64 + lane) * HS + 4 * c + 3];
        const float* __restrict__ w = Wl + c * 256 + col0;
#pragma unroll
        for (int j = 0; j < 16; ++j) {
            float wa = w[j], wb = w[64 + j], wc = w[128 + j], wd = w[192 + j];
            a0[j] = fmaf(h0, wa, a0[j]);
            a0[j] = fmaf(h1, wb, a0[j]);
            a0[j] = fmaf(h2, wc, a0[j]);
            a0[j] = fmaf(h3, wd, a0[j]);
            a1[j] = fmaf(g0, wa, a1[j]);
            a1[j] = fmaf(g1, wb, a1[j]);
            a1[j] = fmaf(g2, wc, a1[j]);
            a1[j] = fmaf(g3, wd, a1[j]);
        }
    }
    __syncthreads();
    {
        const float4* __restrict__ s4 = (const float4*)(Ws + 64 * 64);
        float4* __restrict__ d4 = (float4*)Wl;
        for (int i = tid; i < 1024; i += 256) d4[i] = s4[i];
    }
    __syncthreads();

    // ---- P-S + store ----
#pragma unroll
    for (int j = 0; j < 16; ++j) { s0[j] = 0.f; s1[j] = 0.f; }
    for (int c = 0; c < 16; ++c) {
        float h0 = hl[lane * HS + 4 * c + 0];
        float h1 = hl[lane * HS + 4 * c + 1];
        float h2 = hl[lane * HS + 4 * c + 2];
        float h3 = hl[lane * HS + 4 * c + 3];
        float g0 = hl[(64 + lane) * HS + 4 * c + 0];
        float g1 = hl[(64 + lane) * HS + 4 * c + 1];
        float g2 = hl[(64 + lane) * HS + 4 * c + 2];
        float g3 = hl[(64 + lane) * HS + 4 * c + 3];
        const float* __restrict__ w = Wl + c * 256 + col0;
#pragma unroll
        for (int j = 0; j < 16; ++j) {
            float wa = w[j], wb = w[64 + j], wc = w[128 + j], wd = w[192 + j];
            s0[j] = fmaf(h0, wa, s0[j]);
            s0[j] = fmaf(h1, wb, s0[j]);
            s0[j] = fmaf(h2, wc, s0[j]);
            s0[j] = fmaf(h3, wd, s0[j]);
            s1[j] = fmaf(g0, wa, s1[j]);
            s1[j] = fmaf(g1, wb, s1[j]);
            s1[j] = fmaf(g2, wc, s1[j]);
            s1[j] = fmaf(g3, wd, s1[j]);
        }
    }
    if (act0) {
        uint4* __restrict__ pp = (uint4*)(P + (size_t)n0 * 64 + col0);
#pragma unroll
        for (int q = 0; q < 4; ++q) {
            uint4 pk;
            pk.x = f2bf_rne(a0[q * 4])     | (f2bf_rne(s0[q * 4]) << 16);
            pk.y = f2bf_rne(a0[q * 4 + 1]) | (f2bf_rne(s0[q * 4 + 1]) << 16);
            pk.z = f2bf_rne(a0[q * 4 + 2]) | (f2bf_rne(s0[q * 4 + 2]) << 16);
            pk.w = f2bf_rne(a0[q * 4 + 3]) | (f2bf_rne(s0[q * 4 + 3]) << 16);
            pp[q] = pk;
        }
    }
    if (act1) {
        uint4* __restrict__ pp = (uint4*)(P + (size_t)n1 * 64 + col0);
#pragma unroll
        for (int q = 0; q < 4; ++q) {
            uint4 pk;
            pk.x = f2bf_rne(a1[q * 4])     | (f2bf_rne(s1[q * 4]) << 16);
            pk.y = f2bf_rne(a1[q * 4 + 1]) | (f2bf_rne(s1[q * 4 + 1]) << 16);
            pk.z = f2bf_rne(a1[q * 4 + 2]) | (f2bf_rne(s1[q * 4 + 2]) << 16);
            pk.w = f2bf_rne(a1[q * 4 + 3]) | (f2bf_rne(s1[q * 4 + 3]) << 16);
            pp[q] = pk;
        }
    }
    __syncthreads();
    {
        const float4* __restrict__ s4 = (const float4*)Wf;
        float4* __restrict__ d4 = (float4*)Wl;
        for (int i = tid; i < 1024; i += 256) d4[i] = s4[i];
    }
    __syncthreads();

    // ---- Q-F ----
#pragma unroll
    for (int j = 0; j < 16; ++j) { a0[j] = bfv[col0 + j]; a1[j] = a0[j]; }
    for (int c = 0; c < 16; ++c) {
        float h0 = hl[lane * HS + 4 * c + 0];
        float h1 = hl[lane * HS + 4 * c + 1];
        float h2 = hl[lane * HS + 4 * c + 2];
        float h3 = hl[lane * HS + 4 * c + 3];
        float g0 = hl[(64 + lane) * HS + 4 * c + 0];
        float g1 = hl[(64 + lane) * HS + 4 * c + 1];
        float g2 = hl[(64 + lane) * HS + 4 * c + 2];
        float g3 = hl[(64 + lane) * HS + 4 * c + 3];
        const float* __restrict__ w = Wl + c * 256 + col0;
#pragma unroll
        for (int j = 0; j < 16; ++j) {
            float wa = w[j], wb = w[64 + j], wc = w[128 + j], wd = w[192 + j];
            a0[j] = fmaf(h0, wa, a0[j]);
            a0[j] = fmaf(h1, wb, a0[j]);
            a0[j] = fmaf(h2, wc, a0[j]);
            a0[j] = fmaf(h3, wd, a0[j]);
            a1[j] = fmaf(g0, wa, a1[j]);
            a1[j] = fmaf(g1, wb, a1[j]);
            a1[j] = fmaf(g2, wc, a1[j]);
            a1[j] = fmaf(g3, wd, a1[j]);
        }
    }
    __syncthreads();
    {
        const float4* __restrict__ s4 = (const float4*)Ws;
        float4* __restrict__ d4 = (float4*)Wl;
        for (int i = tid; i < 1024; i += 256) d4[i] = s4[i];
    }
    __syncthreads();

    // ---- Q-S + store ----
#pragma unroll
    for (int j = 0; j < 16; ++j) { s0[j] = bsv[col0 + j]; s1[j] = s0[j]; }
    for (int c = 0; c < 16; ++c) {
        float h0 = hl[lane * HS + 4 * c + 0];
        float h1 = hl[lane * HS + 4 * c + 1];
        float h2 = hl[lane * HS + 4 * c + 2];
        float h3 = hl[lane * HS + 4 * c + 3];
        float g0 = hl[(64 + lane) * HS + 4 * c + 0];
        float g1 = hl[(64 + lane) * HS + 4 * c + 1];
        float g2 = hl[(64 + lane) * HS + 4 * c + 2];
        float g3 = hl[(64 + lane) * HS + 4 * c + 3];
        const float* __restrict__ w = Wl + c * 256 + col0;
#pragma unroll
        for (int j = 0; j < 16; ++j) {
            float wa = w[j], wb = w[64 + j], wc = w[128 + j], wd = w[192 + j];
            s0[j] = fmaf(h0, wa, s0[j]);
            s0[j] = fmaf(h1, wb, s0[j]);
            s0[j] = fmaf(h2, wc, s0[j]);
            s0[j] = fmaf(h3, wd, s0[j]);
            s1[j] = fmaf(g0, wa, s1[j]);
            s1[j] = fmaf(g1, wb, s1[j]);
            s1[j] = fmaf(g2, wc, s1[j]);
            s1[j] = fmaf(g3, wd, s1[j]);
        }
    }
    if (act0) {
        float4* __restrict__ qp = (float4*)(Q + (size_t)n0 * 128 + col0 * 2);
#pragma unroll
        for (int q = 0; q < 8; ++q)
            qp[q] = make_float4(a0[q * 2], s0[q * 2], a0[q * 2 + 1], s0[q * 2 + 1]);
    }
    if (act1) {
        float4* __restrict__ qp = (float4*)(Q + (size_t)n1 * 128 + col0 * 2);
#pragma unroll
        for (int q = 0; q < 8; ++q)
            qp[q] = make_float4(a1[q * 2], s1[q * 2], a1[q * 2 + 1], s1[q * 2 + 1]);
    }
}

// ---------------------------------------------------------------------------
// In-degree histogram (int)
// ---------------------------------------------------------------------------
__global__ __launch_bounds__(256) void deg_kernel(
    const int* __restrict__ dst, int* __restrict__ deg, int E)
{
    int e = blockIdx.x * blockDim.x + threadIdx.x;
    if (e < E) atomicAdd(&deg[dst[e]], 1);
}

// ---------------------------------------------------------------------------
// Three-phase exclusive scan over deg -> rowptr, cursor
// ---------------------------------------------------------------------------
__global__ __launch_bounds__(1024) void scanA_kernel(
    const int* __restrict__ deg, int* __restrict__ iscan,
    int* __restrict__ bsum, int N)
{
    __shared__ int lds[1024];
    int tid = threadIdx.x;
    int gid = blockIdx.x * 1024 + tid;
    int v = (gid < N) ? deg[gid] : 0;
    lds[tid] = v; __syncthreads();
    for (int off = 1; off < 1024; off <<= 1) {
        int t = (tid >= off) ? lds[tid - off] : 0;
        __syncthreads();
        lds[tid] += t;
        __syncthreads();
    }
    if (gid < N) iscan[gid] = lds[tid];
    if (tid == 1023) bsum[blockIdx.x] = lds[1023];
}

__global__ __launch_bounds__(128) void scanB_kernel(
    const int* __restrict__ bsum, int* __restrict__ boff, int nb)
{
    __shared__ int lds[128];
    int t = threadIdx.x;
    int v = (t < nb) ? bsum[t] : 0;
    lds[t] = v; __syncthreads();
    for (int off = 1; off < 128; off <<= 1) {
        int u = (t >= off) ? lds[t - off] : 0;
        __syncthreads();
        lds[t] += u;
        __syncthreads();
    }
    if (t < nb) boff[t] = lds[t] - v;  // exclusive
}

__global__ __launch_bounds__(256) void scanC_kernel(
    const int* __restrict__ iscan, const int* __restrict__ boff,
    const int* __restrict__ deg,
    int* __restrict__ rowptr, int* __restrict__ cursor, int N)
{
    int i = blockIdx.x * blockDim.x + threadIdx.x;
    if (i >= N) return;
    int incl = iscan[i] + boff[i >> 10];
    rowptr[i + 1] = incl;
    cursor[i] = incl - deg[i];
    if (i == 0) rowptr[0] = 0;
}

// ---------------------------------------------------------------------------
// Edge scatter into CSR order, packed (src, ea, dst, 0) int4
// ---------------------------------------------------------------------------
__global__ __launch_bounds__(256) void escatter_kernel(
    const int* __restrict__ src, const int* __restrict__ dst,
    const float* __restrict__ ea, int* __restrict__ cursor,
    int4* __restrict__ e_sd, int E)
{
    int e = blockIdx.x * blockDim.x + threadIdx.x;
    if (e >= E) return;
    int d = dst[e];
    int pos = atomicAdd(&cursor[d], 1);
    e_sd[pos] = make_int4(src[e], __float_as_int(ea[e]), d, 0);
}

// ---------------------------------------------------------------------------
// R18: edge-parallel CGConv message pass. Each wave owns EC=32 contiguous
// CSR edges (lane = dim): uniform work -> no degree-tail imbalance, 37
// waves/SIMD of TLP (node-wave form was latency-bound at ~5). Runs of equal
// dst within the chunk accumulate in registers; atomicAdd flush on run end
// (avg run = 12 edges -> ~4 flushes/chunk). Per-edge math identical to the
// old edge kernel.
// ---------------------------------------------------------------------------
__global__ __launch_bounds__(256) void edgepar_kernel(
    const int4* __restrict__ e_sd,
    const unsigned int* __restrict__ P,
    const float* __restrict__ Q,
    const float* __restrict__ Wf, const float* __restrict__ Ws,
    float* __restrict__ agg, int E)
{
    const int lane = threadIdx.x & 63;
    const int wid = blockIdx.x * 4 + (threadIdx.x >> 6);
    int c0 = wid * EC;
    if (c0 >= E) return;
    int ce = min(c0 + EC, E);

    const float wf = Wf[128 * 64 + lane];
    const float ws = Ws[128 * 64 + lane];

    int cur = -1;
    float acc = 0.f, qf = 0.f, qs = 0.f;
    for (int c = c0; c < ce; ++c) {
        int4 se = e_sd[c];                         // wave-uniform 16B load
        unsigned int pv = P[(size_t)se.x * 64 + lane];   // gathered dword
        if (se.z != cur) {                         // wave-uniform branch
            if (cur >= 0) atomicAdd(&agg[(size_t)cur * 64 + lane], acc);
            acc = 0.f;
            cur = se.z;
            float2 qv = ((const float2*)Q)[(size_t)cur * 64 + lane];
            qf = qv.x; qs = qv.y;
        }
        float ea = __int_as_float(se.y);
        float pf = __uint_as_float(pv << 16);
        float psv = __uint_as_float(pv & 0xffff0000u);
        float xF = fmaf(ea, wf, qf + pf);
        float xS = fmaf(ea, ws, qs + psv);
        float sig = __builtin_amdgcn_rcpf(1.f + __expf(-xF));
        float t = __expf(-fabsf(xS));
        float sp = fmaxf(xS, 0.f) + __logf(1.f + t);
        acc = fmaf(sig, sp, acc);
    }
    atomicAdd(&agg[(size_t)cur * 64 + lane], acc);
}

// ---------------------------------------------------------------------------
// Finalize: hout = relu(hin + agg/deg), and re-zero agg for the next layer.
// ---------------------------------------------------------------------------
__global__ __launch_bounds__(256) void finalize_kernel(
    const float* __restrict__ hin, const int* __restrict__ deg,
    float* __restrict__ agg, float* __restrict__ hout, int total)
{
    int i = blockIdx.x * 256 + threadIdx.x;
    if (i >= total) return;
    int n = i >> 6;
    float a = agg[i];
    agg[i] = 0.f;
    float inv = 1.f / (float)max(deg[n], 1);
    hout[i] = fmaxf(hin[i] + a * inv, 0.f);
}

// ---------------------------------------------------------------------------
// Graph segment starts: bm sorted; gstart[b] = first node of graph b.
// ---------------------------------------------------------------------------
__global__ __launch_bounds__(256) void gstart_kernel(
    const int* __restrict__ bm, int* __restrict__ gstart, int N)
{
    int i = blockIdx.x * blockDim.x + threadIdx.x;
    if (i >= N) return;
    int b = bm[i];
    int prev = (i == 0) ? -1 : bm[i - 1];
    for (int g = prev + 1; g <= b; ++g) gstart[g] = i;
    if (i == N - 1)
        for (int g = b + 1; g <= GB; ++g) gstart[g] = N;
}

// ---------------------------------------------------------------------------
// Segmented mean pool: one block per graph, no atomics.
// ---------------------------------------------------------------------------
__global__ __launch_bounds__(256) void pool_seg_kernel(
    const float* __restrict__ h, const int* __restrict__ gstart,
    float* __restrict__ g)
{
    int b = blockIdx.x;
    int s = gstart[b], e = gstart[b + 1];
    int d = threadIdx.x & 63;
    int w = threadIdx.x >> 6;
    float acc = 0.f;
    for (int n = s + w; n < e; n += 4)
        acc += h[(size_t)n * 64 + d];
    __shared__ float lds[256];
    lds[threadIdx.x] = acc;
    __syncthreads();
    if (w == 0) {
        acc = lds[d] + lds[64 + d] + lds[128 + d] + lds[192 + d];
        g[b * 64 + d] = acc / fmaxf((float)(e - s), 1.f);
    }
}

// ---------------------------------------------------------------------------
// Fused post-MLP (3 relu layers) + final dot + bias. One wave per graph.
// ---------------------------------------------------------------------------
__global__ __launch_bounds__(256) void postmlp_kernel(
    const float* __restrict__ g,
    const float* __restrict__ W0, const float* __restrict__ b0,
    const float* __restrict__ W1, const float* __restrict__ b1,
    const float* __restrict__ W2, const float* __restrict__ b2,
    const float* __restrict__ Wfin, const float* __restrict__ bfin,
    float* __restrict__ out)
{
    int b = blockIdx.x * 4 + (threadIdx.x >> 6);   // 32 blocks x 4 waves = 128
    int d = threadIdx.x & 63;
    float h = g[(size_t)b * 64 + d];

    float acc = b0[d];
#pragma unroll
    for (int k = 0; k < 64; ++k)
        acc = fmaf(__shfl(h, k, 64), W0[k * 64 + d], acc);
    h = fmaxf(acc, 0.f);

    acc = b1[d];
#pragma unroll
    for (int k = 0; k < 64; ++k)
        acc = fmaf(__shfl(h, k, 64), W1[k * 64 + d], acc);
    h = fmaxf(acc, 0.f);

    acc = b2[d];
#pragma unroll
    for (int k = 0; k < 64; ++k)
        acc = fmaf(__shfl(h, k, 64), W2[k * 64 + d], acc);
    h = fmaxf(acc, 0.f);

    float v = h * Wfin[d];
#pragma unroll
    for (int off = 32; off >= 1; off >>= 1)
        v += __shfl_xor(v, off, 64);
    if (d == 0) out[b] = v + bfin[0];
}

extern "C" void kernel_launch(void* const* d_in, const int* in_sizes, int n_in,
                              void* d_out, int out_size, void* d_ws, size_t ws_size,
                              hipStream_t stream)
{
    const float* X      = (const float*)d_in[0];
    const int*   eidx   = (const int*)d_in[1];
    const float* ea     = (const float*)d_in[3];
    const int*   bm     = (const int*)d_in[4];
    const float* pre_W0 = (const float*)d_in[5];
    const float* pre_b0 = (const float*)d_in[6];
    const float* pre_W1 = (const float*)d_in[7];
    const float* pre_b1 = (const float*)d_in[8];
    const float* pre_W2 = (const float*)d_in[9];
    const float* pre_b2 = (const float*)d_in[10];
    const float* cg_Wf  = (const float*)d_in[11];
    const float* cg_bf  = (const float*)d_in[12];
    const float* cg_Ws  = (const float*)d_in[13];
    const float* cg_bs  = (const float*)d_in[14];
    const float* post_W0 = (const float*)d_in[15];
    const float* post_b0 = (const float*)d_in[16];
    const float* post_W1 = (const float*)d_in[17];
    const float* post_b1 = (const float*)d_in[18];
    const float* post_W2 = (const float*)d_in[19];
    const float* post_b2 = (const float*)d_in[20];
    const float* post_Wf = (const float*)d_in[21];
    const float* post_bf = (const float*)d_in[22];

    const int* src = eidx;
    const int* dst = eidx + GE;

    // ---- workspace carve-up (16B-aligned big arrays first) ----
    const size_t N64 = (size_t)GN * 64;
    float* hA    = (float*)d_ws;                  // N*64
    float* hB    = hA + N64;                      // N*64
    unsigned int* P = (unsigned int*)(hB + N64);  // N*64 packed bf16x2
    float* agg   = (float*)(P + N64);             // N*64 message accumulator
    float* Q     = agg + N64;                     // N*128 fp32 (qf,qs) pairs
    int4* e_sd   = (int4*)(Q + (size_t)GN * 128); // E int4 (16B-aligned)
    int* deg_i   = (int*)(e_sd + GE);             // N
    int* iscan   = deg_i + GN;                    // N
    int* bsum    = iscan + GN;                    // 128
    int* boff    = bsum + 128;                    // 128
    int* rowptr  = boff + 128;                    // N+2
    int* cursor  = rowptr + GN + 2;               // N
    int* gstart  = cursor + GN;                   // B+1
    float* g0    = (float*)(gstart + GB + 1);     // B*64

    const int TPB = 256;
    int gridE  = (GE + TPB - 1) / TPB;
    int gridN  = (GN + TPB - 1) / TPB;            // 391
    int gridP  = (GN + 127) / 128;                // 782 (dense col-split grid)
    int gridND = ((GN * 64) + TPB - 1) / TPB;     // 25000 (finalize grid)
    int gridEP = (GE + EC * 4 - 1) / (EC * 4);    // 9375 (edge-parallel grid)
    int scanBlocks = (GN + 1023) / 1024;          // 98

    // per-layer weight pointers
    const float* Wf0 = cg_Wf;
    const float* Ws0 = cg_Ws;
    const float* Wf1 = cg_Wf + (size_t)1 * GZ * GD;
    const float* Ws1 = cg_Ws + (size_t)1 * GZ * GD;
    const float* Wf2 = cg_Wf + (size_t)2 * GZ * GD;
    const float* Ws2 = cg_Ws + (size_t)2 * GZ * GD;

    // fused pre-MLP (R14 col-split) + P0 + Q0
    premlp_kernel<<<gridP, TPB, 0, stream>>>(
        X, pre_W0, pre_b0, pre_W1, pre_b1, pre_W2, pre_b2,
        Wf0, Ws0, Wf0 + 64 * 64, Ws0 + 64 * 64, cg_bf, cg_bs,
        hA, P, Q, GN);

    // zero accumulators + degree + CSR build
    hipMemsetAsync(deg_i, 0, GN * sizeof(int), stream);
    hipMemsetAsync(agg, 0, N64 * sizeof(float), stream);
    deg_kernel<<<gridE, TPB, 0, stream>>>(dst, deg_i, GE);
    scanA_kernel<<<scanBlocks, 1024, 0, stream>>>(deg_i, iscan, bsum, GN);
    scanB_kernel<<<1, 128, 0, stream>>>(bsum, boff, scanBlocks);
    scanC_kernel<<<gridN, TPB, 0, stream>>>(iscan, boff, deg_i, rowptr, cursor, GN);
    escatter_kernel<<<gridE, TPB, 0, stream>>>(src, dst, ea, cursor, e_sd, GE);

    // graph segment starts (bm sorted)
    gstart_kernel<<<gridN, TPB, 0, stream>>>(bm, gstart, GN);

    // ---- CGConv layer 0 ----
    edgepar_kernel<<<gridEP, TPB, 0, stream>>>(e_sd, P, Q, Wf0, Ws0, agg, GE);
    finalize_kernel<<<gridND, TPB, 0, stream>>>(hA, deg_i, agg, hB, GN * 64);
    pjq_kernel<<<gridP, TPB, 0, stream>>>(
        hB, Wf1, Ws1, cg_bf + GD, cg_bs + GD, P, Q, GN);

    // ---- CGConv layer 1 ----
    edgepar_kernel<<<gridEP, TPB, 0, stream>>>(e_sd, P, Q, Wf1, Ws1, agg, GE);
    finalize_kernel<<<gridND, TPB, 0, stream>>>(hB, deg_i, agg, hA, GN * 64);
    pjq_kernel<<<gridP, TPB, 0, stream>>>(
        hA, Wf2, Ws2, cg_bf + 2 * GD, cg_bs + 2 * GD, P, Q, GN);

    // ---- CGConv layer 2 ----
    edgepar_kernel<<<gridEP, TPB, 0, stream>>>(e_sd, P, Q, Wf2, Ws2, agg, GE);
    finalize_kernel<<<gridND, TPB, 0, stream>>>(hA, deg_i, agg, hB, GN * 64);

    // segmented mean pool (no atomics)
    pool_seg_kernel<<<GB, TPB, 0, stream>>>(hB, gstart, g0);

    // fused post-MLP + final projection
    postmlp_kernel<<<GB / 4, TPB, 0, stream>>>(
        g0, post_W0, post_b0, post_W1, post_b1, post_W2, post_b2,
        post_Wf, post_bf, (float*)d_out);
}

// Round 9
// 889.067 us; speedup vs baseline: 4.2286x; 1.1674x over previous
//
#include <hip/hip_runtime.h>
#include <hip/hip_bf16.h>
#include <math.h>

// Problem constants (fixed by the reference)
#define GN 100000   // nodes
#define GE 1200000  // edges
#define GB 128      // graphs
#define GF 92       // raw features
#define GD 64       // hidden dim
#define GL 3        // CGConv layers
#define GZ 129      // 2*D+1

#define HS 65       // padded LDS h-tile stride (2-way bank alias = free)

// round-to-nearest-even fp32 -> bf16 (returned in low 16 bits)
__device__ __forceinline__ unsigned int f2bf_rne(float x)
{
    unsigned int u = __float_as_uint(x);
    u += 0x7fffu + ((u >> 16) & 1u);
    return u >> 16;
}

// ---------------------------------------------------------------------------
// Fused pre-MLP (3 layers) + P0 + Q0.  (R14 form -- measured best: ~160us.)
// 4-way column split (wave = 16-col slice), R=2 nodes/thread, weights + h
// tile staged in LDS.
// ---------------------------------------------------------------------------
__global__ __launch_bounds__(256, 2) void premlp_kernel(
    const float* __restrict__ X,
    const float* __restrict__ W0, const float* __restrict__ b0,
    const float* __restrict__ W1, const float* __restrict__ b1,
    const float* __restrict__ W2, const float* __restrict__ b2,
    const float* __restrict__ WfD, const float* __restrict__ WsD,   // rows 0..63
    const float* __restrict__ WfS, const float* __restrict__ WsS,   // rows 64..127
    const float* __restrict__ bf, const float* __restrict__ bs,
    float* __restrict__ hout, unsigned int* __restrict__ Pout,
    float* __restrict__ Qout, int N)
{
    __shared__ __align__(16) float Wl[5888];    // 23 KB weight stage (W0 needs it all)
    __shared__ float hl[128 * HS];              // 33.3 KB padded h tile (128 nodes)
    const int tid = threadIdx.x;
    const int lane = tid & 63;
    const int col0 = (tid >> 6) * 16;           // this wave's column slice
    const int base = blockIdx.x * 128;
    const int n0 = base + lane;
    const int n1 = base + 64 + lane;
    const int nn0 = (n0 < N) ? n0 : (N - 1);
    const int nn1 = (n1 < N) ? n1 : (N - 1);
    const bool act0 = (n0 < N), act1 = (n1 < N);

    float a0[16], a1[16], s0[16], s1[16];

    // ---- stage W0 (92x64 = 1472 float4) ----
    {
        const float4* __restrict__ s4 = (const float4*)W0;
        float4* __restrict__ d4 = (float4*)Wl;
        for (int i = tid; i < 1472; i += 256) d4[i] = s4[i];
    }
    __syncthreads();

    // ---- layer 0: K=92 ----
#pragma unroll
    for (int j = 0; j < 16; ++j) { a0[j] = b0[col0 + j]; a1[j] = a0[j]; }
    {
        const float4* __restrict__ r40 = (const float4*)(X + (size_t)nn0 * GF);
        const float4* __restrict__ r41 = (const float4*)(X + (size_t)nn1 * GF);
        for (int c = 0; c < 23; ++c) {
            float4 v0 = r40[c];
            float4 v1 = r41[c];
            const float* __restrict__ w = Wl + c * 256 + col0;
#pragma unroll
            for (int j = 0; j < 16; ++j) {
                float wa = w[j], wb = w[64 + j], wc = w[128 + j], wd = w[192 + j];
                a0[j] = fmaf(v0.x, wa, a0[j]);
                a0[j] = fmaf(v0.y, wb, a0[j]);
                a0[j] = fmaf(v0.z, wc, a0[j]);
                a0[j] = fmaf(v0.w, wd, a0[j]);
                a1[j] = fmaf(v1.x, wa, a1[j]);
                a1[j] = fmaf(v1.y, wb, a1[j]);
                a1[j] = fmaf(v1.z, wc, a1[j]);
                a1[j] = fmaf(v1.w, wd, a1[j]);
            }
        }
    }
    __syncthreads();    // all Wl reads done
#pragma unroll
    for (int j = 0; j < 16; ++j) {
        hl[lane * HS + col0 + j] = fmaxf(a0[j], 0.f);
        hl[(64 + lane) * HS + col0 + j] = fmaxf(a1[j], 0.f);
    }
    {
        const float4* __restrict__ s4 = (const float4*)W1;
        float4* __restrict__ d4 = (float4*)Wl;
        for (int i = tid; i < 1024; i += 256) d4[i] = s4[i];
    }
    __syncthreads();

    // ---- layer 1 ----
#pragma unroll
    for (int j = 0; j < 16; ++j) { a0[j] = b1[col0 + j]; a1[j] = a0[j]; }
    for (int c = 0; c < 16; ++c) {
        float h0 = hl[lane * HS + 4 * c + 0];
        float h1 = hl[lane * HS + 4 * c + 1];
        float h2 = hl[lane * HS + 4 * c + 2];
        float h3 = hl[lane * HS + 4 * c + 3];
        float g0 = hl[(64 + lane) * HS + 4 * c + 0];
        float g1 = hl[(64 + lane) * HS + 4 * c + 1];
        float g2 = hl[(64 + lane) * HS + 4 * c + 2];
        float g3 = hl[(64 + lane) * HS + 4 * c + 3];
        const float* __restrict__ w = Wl + c * 256 + col0;
#pragma unroll
        for (int j = 0; j < 16; ++j) {
            float wa = w[j], wb = w[64 + j], wc = w[128 + j], wd = w[192 + j];
            a0[j] = fmaf(h0, wa, a0[j]);
            a0[j] = fmaf(h1, wb, a0[j]);
            a0[j] = fmaf(h2, wc, a0[j]);
            a0[j] = fmaf(h3, wd, a0[j]);
            a1[j] = fmaf(g0, wa, a1[j]);
            a1[j] = fmaf(g1, wb, a1[j]);
            a1[j] = fmaf(g2, wc, a1[j]);
            a1[j] = fmaf(g3, wd, a1[j]);
        }
    }
    __syncthreads();
#pragma unroll
    for (int j = 0; j < 16; ++j) {
        hl[lane * HS + col0 + j] = fmaxf(a0[j], 0.f);
        hl[(64 + lane) * HS + col0 + j] = fmaxf(a1[j], 0.f);
    }
    {
        const float4* __restrict__ s4 = (const float4*)W2;
        float4* __restrict__ d4 = (float4*)Wl;
        for (int i = tid; i < 1024; i += 256) d4[i] = s4[i];
    }
    __syncthreads();

    // ---- layer 2 ----
#pragma unroll
    for (int j = 0; j < 16; ++j) { a0[j] = b2[col0 + j]; a1[j] = a0[j]; }
    for (int c = 0; c < 16; ++c) {
        float h0 = hl[lane * HS + 4 * c + 0];
        float h1 = hl[lane * HS + 4 * c + 1];
        float h2 = hl[lane * HS + 4 * c + 2];
        float h3 = hl[lane * HS + 4 * c + 3];
        float g0 = hl[(64 + lane) * HS + 4 * c + 0];
        float g1 = hl[(64 + lane) * HS + 4 * c + 1];
        float g2 = hl[(64 + lane) * HS + 4 * c + 2];
        float g3 = hl[(64 + lane) * HS + 4 * c + 3];
        const float* __restrict__ w = Wl + c * 256 + col0;
#pragma unroll
        for (int j = 0; j < 16; ++j) {
            float wa = w[j], wb = w[64 + j], wc = w[128 + j], wd = w[192 + j];
            a0[j] = fmaf(h0, wa, a0[j]);
            a0[j] = fmaf(h1, wb, a0[j]);
            a0[j] = fmaf(h2, wc, a0[j]);
            a0[j] = fmaf(h3, wd, a0[j]);
            a1[j] = fmaf(g0, wa, a1[j]);
            a1[j] = fmaf(g1, wb, a1[j]);
            a1[j] = fmaf(g2, wc, a1[j]);
            a1[j] = fmaf(g3, wd, a1[j]);
        }
    }
    __syncthreads();
#pragma unroll
    for (int j = 0; j < 16; ++j) {
        hl[lane * HS + col0 + j] = fmaxf(a0[j], 0.f);
        hl[(64 + lane) * HS + col0 + j] = fmaxf(a1[j], 0.f);
    }
    if (act0) {
        float4* __restrict__ op = (float4*)(hout + (size_t)n0 * 64 + col0);
#pragma unroll
        for (int q = 0; q < 4; ++q)
            op[q] = make_float4(fmaxf(a0[q * 4], 0.f), fmaxf(a0[q * 4 + 1], 0.f),
                                fmaxf(a0[q * 4 + 2], 0.f), fmaxf(a0[q * 4 + 3], 0.f));
    }
    if (act1) {
        float4* __restrict__ op = (float4*)(hout + (size_t)n1 * 64 + col0);
#pragma unroll
        for (int q = 0; q < 4; ++q)
            op[q] = make_float4(fmaxf(a1[q * 4], 0.f), fmaxf(a1[q * 4 + 1], 0.f),
                                fmaxf(a1[q * 4 + 2], 0.f), fmaxf(a1[q * 4 + 3], 0.f));
    }
    {
        const float4* __restrict__ s4 = (const float4*)WfS;
        float4* __restrict__ d4 = (float4*)Wl;
        for (int i = tid; i < 1024; i += 256) d4[i] = s4[i];
    }
    __syncthreads();

    // ---- P0-F ----
#pragma unroll
    for (int j = 0; j < 16; ++j) { a0[j] = 0.f; a1[j] = 0.f; }
    for (int c = 0; c < 16; ++c) {
        float h0 = hl[lane * HS + 4 * c + 0];
        float h1 = hl[lane * HS + 4 * c + 1];
        float h2 = hl[lane * HS + 4 * c + 2];
        float h3 = hl[lane * HS + 4 * c + 3];
        float g0 = hl[(64 + lane) * HS + 4 * c + 0];
        float g1 = hl[(64 + lane) * HS + 4 * c + 1];
        float g2 = hl[(64 + lane) * HS + 4 * c + 2];
        float g3 = hl[(64 + lane) * HS + 4 * c + 3];
        const float* __restrict__ w = Wl + c * 256 + col0;
#pragma unroll
        for (int j = 0; j < 16; ++j) {
            float wa = w[j], wb = w[64 + j], wc = w[128 + j], wd = w[192 + j];
            a0[j] = fmaf(h0, wa, a0[j]);
            a0[j] = fmaf(h1, wb, a0[j]);
            a0[j] = fmaf(h2, wc, a0[j]);
            a0[j] = fmaf(h3, wd, a0[j]);
            a1[j] = fmaf(g0, wa, a1[j]);
            a1[j] = fmaf(g1, wb, a1[j]);
            a1[j] = fmaf(g2, wc, a1[j]);
            a1[j] = fmaf(g3, wd, a1[j]);
        }
    }
    __syncthreads();
    {
        const float4* __restrict__ s4 = (const float4*)WsS;
        float4* __restrict__ d4 = (float4*)Wl;
        for (int i = tid; i < 1024; i += 256) d4[i] = s4[i];
    }
    __syncthreads();

    // ---- P0-S + store ----
#pragma unroll
    for (int j = 0; j < 16; ++j) { s0[j] = 0.f; s1[j] = 0.f; }
    for (int c = 0; c < 16; ++c) {
        float h0 = hl[lane * HS + 4 * c + 0];
        float h1 = hl[lane * HS + 4 * c + 1];
        float h2 = hl[lane * HS + 4 * c + 2];
        float h3 = hl[lane * HS + 4 * c + 3];
        float g0 = hl[(64 + lane) * HS + 4 * c + 0];
        float g1 = hl[(64 + lane) * HS + 4 * c + 1];
        float g2 = hl[(64 + lane) * HS + 4 * c + 2];
        float g3 = hl[(64 + lane) * HS + 4 * c + 3];
        const float* __restrict__ w = Wl + c * 256 + col0;
#pragma unroll
        for (int j = 0; j < 16; ++j) {
            float wa = w[j], wb = w[64 + j], wc = w[128 + j], wd = w[192 + j];
            s0[j] = fmaf(h0, wa, s0[j]);
            s0[j] = fmaf(h1, wb, s0[j]);
            s0[j] = fmaf(h2, wc, s0[j]);
            s0[j] = fmaf(h3, wd, s0[j]);
            s1[j] = fmaf(g0, wa, s1[j]);
            s1[j] = fmaf(g1, wb, s1[j]);
            s1[j] = fmaf(g2, wc, s1[j]);
            s1[j] = fmaf(g3, wd, s1[j]);
        }
    }
    if (act0) {
        uint4* __restrict__ pp = (uint4*)(Pout + (size_t)n0 * 64 + col0);
#pragma unroll
        for (int q = 0; q < 4; ++q) {
            uint4 pk;
            pk.x = f2bf_rne(a0[q * 4])     | (f2bf_rne(s0[q * 4]) << 16);
            pk.y = f2bf_rne(a0[q * 4 + 1]) | (f2bf_rne(s0[q * 4 + 1]) << 16);
            pk.z = f2bf_rne(a0[q * 4 + 2]) | (f2bf_rne(s0[q * 4 + 2]) << 16);
            pk.w = f2bf_rne(a0[q * 4 + 3]) | (f2bf_rne(s0[q * 4 + 3]) << 16);
            pp[q] = pk;
        }
    }
    if (act1) {
        uint4* __restrict__ pp = (uint4*)(Pout + (size_t)n1 * 64 + col0);
#pragma unroll
        for (int q = 0; q < 4; ++q) {
            uint4 pk;
            pk.x = f2bf_rne(a1[q * 4])     | (f2bf_rne(s1[q * 4]) << 16);
            pk.y = f2bf_rne(a1[q * 4 + 1]) | (f2bf_rne(s1[q * 4 + 1]) << 16);
            pk.z = f2bf_rne(a1[q * 4 + 2]) | (f2bf_rne(s1[q * 4 + 2]) << 16);
            pk.w = f2bf_rne(a1[q * 4 + 3]) | (f2bf_rne(s1[q * 4 + 3]) << 16);
            pp[q] = pk;
        }
    }
    __syncthreads();
    {
        const float4* __restrict__ s4 = (const float4*)WfD;
        float4* __restrict__ d4 = (float4*)Wl;
        for (int i = tid; i < 1024; i += 256) d4[i] = s4[i];
    }
    __syncthreads();

    // ---- Q0-F ----
#pragma unroll
    for (int j = 0; j < 16; ++j) { a0[j] = bf[col0 + j]; a1[j] = a0[j]; }
    for (int c = 0; c < 16; ++c) {
        float h0 = hl[lane * HS + 4 * c + 0];
        float h1 = hl[lane * HS + 4 * c + 1];
        float h2 = hl[lane * HS + 4 * c + 2];
        float h3 = hl[lane * HS + 4 * c + 3];
        float g0 = hl[(64 + lane) * HS + 4 * c + 0];
        float g1 = hl[(64 + lane) * HS + 4 * c + 1];
        float g2 = hl[(64 + lane) * HS + 4 * c + 2];
        float g3 = hl[(64 + lane) * HS + 4 * c + 3];
        const float* __restrict__ w = Wl + c * 256 + col0;
#pragma unroll
        for (int j = 0; j < 16; ++j) {
            float wa = w[j], wb = w[64 + j], wc = w[128 + j], wd = w[192 + j];
            a0[j] = fmaf(h0, wa, a0[j]);
            a0[j] = fmaf(h1, wb, a0[j]);
            a0[j] = fmaf(h2, wc, a0[j]);
            a0[j] = fmaf(h3, wd, a0[j]);
            a1[j] = fmaf(g0, wa, a1[j]);
            a1[j] = fmaf(g1, wb, a1[j]);
            a1[j] = fmaf(g2, wc, a1[j]);
            a1[j] = fmaf(g3, wd, a1[j]);
        }
    }
    __syncthreads();
    {
        const float4* __restrict__ s4 = (const float4*)WsD;
        float4* __restrict__ d4 = (float4*)Wl;
        for (int i = tid; i < 1024; i += 256) d4[i] = s4[i];
    }
    __syncthreads();

    // ---- Q0-S + store ----
#pragma unroll
    for (int j = 0; j < 16; ++j) { s0[j] = bs[col0 + j]; s1[j] = s0[j]; }
    for (int c = 0; c < 16; ++c) {
        float h0 = hl[lane * HS + 4 * c + 0];
        float h1 = hl[lane * HS + 4 * c + 1];
        float h2 = hl[lane * HS + 4 * c + 2];
        float h3 = hl[lane * HS + 4 * c + 3];
        float g0 = hl[(64 + lane) * HS + 4 * c + 0];
        float g1 = hl[(64 + lane) * HS + 4 * c + 1];
        float g2 = hl[(64 + lane) * HS + 4 * c + 2];
        float g3 = hl[(64 + lane) * HS + 4 * c + 3];
        const float* __restrict__ w = Wl + c * 256 + col0;
#pragma unroll
        for (int j = 0; j < 16; ++j) {
            float wa = w[j], wb = w[64 + j], wc = w[128 + j], wd = w[192 + j];
            s0[j] = fmaf(h0, wa, s0[j]);
            s0[j] = fmaf(h1, wb, s0[j]);
            s0[j] = fmaf(h2, wc, s0[j]);
            s0[j] = fmaf(h3, wd, s0[j]);
            s1[j] = fmaf(g0, wa, s1[j]);
            s1[j] = fmaf(g1, wb, s1[j]);
            s1[j] = fmaf(g2, wc, s1[j]);
            s1[j] = fmaf(g3, wd, s1[j]);
        }
    }
    if (act0) {
        float4* __restrict__ qp = (float4*)(Qout + (size_t)n0 * 128 + col0 * 2);
#pragma unroll
        for (int q = 0; q < 8; ++q)
            qp[q] = make_float4(a0[q * 2], s0[q * 2], a0[q * 2 + 1], s0[q * 2 + 1]);
    }
    if (act1) {
        float4* __restrict__ qp = (float4*)(Qout + (size_t)n1 * 128 + col0 * 2);
#pragma unroll
        for (int q = 0; q < 8; ++q)
            qp[q] = make_float4(a1[q * 2], s1[q * 2], a1[q * 2 + 1], s1[q * 2 + 1]);
    }
}

// ---------------------------------------------------------------------------
// Gate projections: P (src half, packed bf16) and Q (dst half + bias, fp32).
// R19 rewrite: h rows read directly from GLOBAL (pure input -> no hazard;
// VMEM pipe instead of LDS), both gate halves staged at once (32 KB -> only
// 3 barriers vs 6), dual-gate compute (256 FMA per 32 LDS-b128 per c, ratio
// 8:1 vs R14's 5.3:1). R=2 nodes/thread. Per-output FMA order unchanged.
// ---------------------------------------------------------------------------
__global__ __launch_bounds__(256, 3) void pjq_kernel(
    const float* __restrict__ h,
    const float* __restrict__ Wf, const float* __restrict__ Ws,
    const float* __restrict__ bfv, const float* __restrict__ bsv,
    unsigned int* __restrict__ P, float* __restrict__ Q, int N)
{
    __shared__ __align__(16) float Wl[8192];   // 32 KB: gate-F half | gate-S half
    const int tid = threadIdx.x;
    const int lane = tid & 63;
    const int col0 = (tid >> 6) * 16;
    const int base = blockIdx.x * 128;
    const int n0 = base + lane;
    const int n1 = base + 64 + lane;
    const int nn0 = (n0 < N) ? n0 : (N - 1);
    const int nn1 = (n1 < N) ? n1 : (N - 1);
    const bool act0 = (n0 < N), act1 = (n1 < N);

    const float4* __restrict__ h40 = (const float4*)(h + (size_t)nn0 * 64);
    const float4* __restrict__ h41 = (const float4*)(h + (size_t)nn1 * 64);

    float aF0[16], aF1[16], aS0[16], aS1[16];

    // ---- stage src-half rows 64..127 of BOTH gates (2048 float4) ----
    {
        const float4* __restrict__ f4 = (const float4*)(Wf + 64 * 64);
        const float4* __restrict__ s4 = (const float4*)(Ws + 64 * 64);
        float4* __restrict__ d4 = (float4*)Wl;
        for (int i = tid; i < 1024; i += 256) {
            d4[i] = f4[i];
            d4[1024 + i] = s4[i];
        }
    }
    __syncthreads();

    // ---- P pass (dual gate) ----
#pragma unroll
    for (int j = 0; j < 16; ++j) { aF0[j] = 0.f; aF1[j] = 0.f; aS0[j] = 0.f; aS1[j] = 0.f; }
    for (int c = 0; c < 16; ++c) {
        float4 v0 = h40[c];
        float4 v1 = h41[c];
        const float* __restrict__ wf = Wl + c * 256 + col0;
        const float* __restrict__ ws = Wl + 4096 + c * 256 + col0;
#pragma unroll
        for (int j = 0; j < 16; ++j) {
            float wa = wf[j], wb = wf[64 + j], wc = wf[128 + j], wd = wf[192 + j];
            aF0[j] = fmaf(v0.x, wa, aF0[j]);
            aF0[j] = fmaf(v0.y, wb, aF0[j]);
            aF0[j] = fmaf(v0.z, wc, aF0[j]);
            aF0[j] = fmaf(v0.w, wd, aF0[j]);
            aF1[j] = fmaf(v1.x, wa, aF1[j]);
            aF1[j] = fmaf(v1.y, wb, aF1[j]);
            aF1[j] = fmaf(v1.z, wc, aF1[j]);
            aF1[j] = fmaf(v1.w, wd, aF1[j]);
            float sa = ws[j], sb = ws[64 + j], sc = ws[128 + j], sd = ws[192 + j];
            aS0[j] = fmaf(v0.x, sa, aS0[j]);
            aS0[j] = fmaf(v0.y, sb, aS0[j]);
            aS0[j] = fmaf(v0.z, sc, aS0[j]);
            aS0[j] = fmaf(v0.w, sd, aS0[j]);
            aS1[j] = fmaf(v1.x, sa, aS1[j]);
            aS1[j] = fmaf(v1.y, sb, aS1[j]);
            aS1[j] = fmaf(v1.z, sc, aS1[j]);
            aS1[j] = fmaf(v1.w, sd, aS1[j]);
        }
    }
    if (act0) {
        uint4* __restrict__ pp = (uint4*)(P + (size_t)n0 * 64 + col0);
#pragma unroll
        for (int q = 0; q < 4; ++q) {
            uint4 pk;
            pk.x = f2bf_rne(aF0[q * 4])     | (f2bf_rne(aS0[q * 4]) << 16);
            pk.y = f2bf_rne(aF0[q * 4 + 1]) | (f2bf_rne(aS0[q * 4 + 1]) << 16);
            pk.z = f2bf_rne(aF0[q * 4 + 2]) | (f2bf_rne(aS0[q * 4 + 2]) << 16);
            pk.w = f2bf_rne(aF0[q * 4 + 3]) | (f2bf_rne(aS0[q * 4 + 3]) << 16);
            pp[q] = pk;
        }
    }
    if (act1) {
        uint4* __restrict__ pp = (uint4*)(P + (size_t)n1 * 64 + col0);
#pragma unroll
        for (int q = 0; q < 4; ++q) {
            uint4 pk;
            pk.x = f2bf_rne(aF1[q * 4])     | (f2bf_rne(aS1[q * 4]) << 16);
            pk.y = f2bf_rne(aF1[q * 4 + 1]) | (f2bf_rne(aS1[q * 4 + 1]) << 16);
            pk.z = f2bf_rne(aF1[q * 4 + 2]) | (f2bf_rne(aS1[q * 4 + 2]) << 16);
            pk.w = f2bf_rne(aF1[q * 4 + 3]) | (f2bf_rne(aS1[q * 4 + 3]) << 16);
            pp[q] = pk;
        }
    }
    __syncthreads();

    // ---- stage dst-half rows 0..63 of BOTH gates ----
    {
        const float4* __restrict__ f4 = (const float4*)Wf;
        const float4* __restrict__ s4 = (const float4*)Ws;
        float4* __restrict__ d4 = (float4*)Wl;
        for (int i = tid; i < 1024; i += 256) {
            d4[i] = f4[i];
            d4[1024 + i] = s4[i];
        }
    }
    __syncthreads();

    // ---- Q pass (dual gate, bias folded) ----
#pragma unroll
    for (int j = 0; j < 16; ++j) {
        aF0[j] = bfv[col0 + j]; aF1[j] = aF0[j];
        aS0[j] = bsv[col0 + j]; aS1[j] = aS0[j];
    }
    for (int c = 0; c < 16; ++c) {
        float4 v0 = h40[c];
        float4 v1 = h41[c];
        const float* __restrict__ wf = Wl + c * 256 + col0;
        const float* __restrict__ ws = Wl + 4096 + c * 256 + col0;
#pragma unroll
        for (int j = 0; j < 16; ++j) {
            float wa = wf[j], wb = wf[64 + j], wc = wf[128 + j], wd = wf[192 + j];
            aF0[j] = fmaf(v0.x, wa, aF0[j]);
            aF0[j] = fmaf(v0.y, wb, aF0[j]);
            aF0[j] = fmaf(v0.z, wc, aF0[j]);
            aF0[j] = fmaf(v0.w, wd, aF0[j]);
            aF1[j] = fmaf(v1.x, wa, aF1[j]);
            aF1[j] = fmaf(v1.y, wb, aF1[j]);
            aF1[j] = fmaf(v1.z, wc, aF1[j]);
            aF1[j] = fmaf(v1.w, wd, aF1[j]);
            float sa = ws[j], sb = ws[64 + j], sc = ws[128 + j], sd = ws[192 + j];
            aS0[j] = fmaf(v0.x, sa, aS0[j]);
            aS0[j] = fmaf(v0.y, sb, aS0[j]);
            aS0[j] = fmaf(v0.z, sc, aS0[j]);
            aS0[j] = fmaf(v0.w, sd, aS0[j]);
            aS1[j] = fmaf(v1.x, sa, aS1[j]);
            aS1[j] = fmaf(v1.y, sb, aS1[j]);
            aS1[j] = fmaf(v1.z, sc, aS1[j]);
            aS1[j] = fmaf(v1.w, sd, aS1[j]);
        }
    }
    if (act0) {
        float4* __restrict__ qp = (float4*)(Q + (size_t)n0 * 128 + col0 * 2);
#pragma unroll
        for (int q = 0; q < 8; ++q)
            qp[q] = make_float4(aF0[q * 2], aS0[q * 2], aF0[q * 2 + 1], aS0[q * 2 + 1]);
    }
    if (act1) {
        float4* __restrict__ qp = (float4*)(Q + (size_t)n1 * 128 + col0 * 2);
#pragma unroll
        for (int q = 0; q < 8; ++q)
            qp[q] = make_float4(aF1[q * 2], aS1[q * 2], aF1[q * 2 + 1], aS1[q * 2 + 1]);
    }
}

// ---------------------------------------------------------------------------
// In-degree histogram (int)
// ---------------------------------------------------------------------------
__global__ __launch_bounds__(256) void deg_kernel(
    const int* __restrict__ dst, int* __restrict__ deg, int E)
{
    int e = blockIdx.x * blockDim.x + threadIdx.x;
    if (e < E) atomicAdd(&deg[dst[e]], 1);
}

// ---------------------------------------------------------------------------
// Three-phase exclusive scan over deg -> rowptr, cursor
// ---------------------------------------------------------------------------
__global__ __launch_bounds__(1024) void scanA_kernel(
    const int* __restrict__ deg, int* __restrict__ iscan,
    int* __restrict__ bsum, int N)
{
    __shared__ int lds[1024];
    int tid = threadIdx.x;
    int gid = blockIdx.x * 1024 + tid;
    int v = (gid < N) ? deg[gid] : 0;
    lds[tid] = v; __syncthreads();
    for (int off = 1; off < 1024; off <<= 1) {
        int t = (tid >= off) ? lds[tid - off] : 0;
        __syncthreads();
        lds[tid] += t;
        __syncthreads();
    }
    if (gid < N) iscan[gid] = lds[tid];
    if (tid == 1023) bsum[blockIdx.x] = lds[1023];
}

__global__ __launch_bounds__(128) void scanB_kernel(
    const int* __restrict__ bsum, int* __restrict__ boff, int nb)
{
    __shared__ int lds[128];
    int t = threadIdx.x;
    int v = (t < nb) ? bsum[t] : 0;
    lds[t] = v; __syncthreads();
    for (int off = 1; off < 128; off <<= 1) {
        int u = (t >= off) ? lds[t - off] : 0;
        __syncthreads();
        lds[t] += u;
        __syncthreads();
    }
    if (t < nb) boff[t] = lds[t] - v;  // exclusive
}

__global__ __launch_bounds__(256) void scanC_kernel(
    const int* __restrict__ iscan, const int* __restrict__ boff,
    const int* __restrict__ deg,
    int* __restrict__ rowptr, int* __restrict__ cursor, int N)
{
    int i = blockIdx.x * blockDim.x + threadIdx.x;
    if (i >= N) return;
    int incl = iscan[i] + boff[i >> 10];
    rowptr[i + 1] = incl;
    cursor[i] = incl - deg[i];
    if (i == 0) rowptr[0] = 0;
}

// ---------------------------------------------------------------------------
// Edge scatter into CSR order, packed (src, ea) int2
// ---------------------------------------------------------------------------
__global__ __launch_bounds__(256) void escatter_kernel(
    const int* __restrict__ src, const int* __restrict__ dst,
    const float* __restrict__ ea, int* __restrict__ cursor,
    int2* __restrict__ e_se, int E)
{
    int e = blockIdx.x * blockDim.x + threadIdx.x;
    if (e >= E) return;
    int pos = atomicAdd(&cursor[dst[e]], 1);
    e_se[pos] = make_int2(src[e], __float_as_int(ea[e]));
}

// ---------------------------------------------------------------------------
// CGConv edge pass. One wave per node, lane = dim. Q precomputed.
// Restored R14 form: measured at its memory-system floor (~130us/layer,
// random 256B P-row gathers); edge-parallel rewrite (R18) was no faster
// and added finalize overhead.
// ---------------------------------------------------------------------------
__global__ __launch_bounds__(256) void edge_kernel(
    const float* __restrict__ h, const int* __restrict__ rowptr,
    const int2* __restrict__ e_se,
    const unsigned int* __restrict__ P,
    const float* __restrict__ Q,
    const float* __restrict__ Wf, const float* __restrict__ Ws,
    float* __restrict__ hout)
{
    int n = blockIdx.x * 4 + (threadIdx.x >> 6);   // grid exactly covers GN
    int d = threadIdx.x & 63;

    const float2 qv = ((const float2*)Q)[(size_t)n * 64 + d];
    float qf = qv.x, qs = qv.y;
    float wf = Wf[128 * 64 + d];
    float ws = Ws[128 * 64 + d];

    size_t idx = (size_t)n * 64 + d;
    float hres = h[idx];

    int rb = rowptr[n], re = rowptr[n + 1];
    float agg = 0.f;
#pragma unroll 8
    for (int p = rb; p < re; ++p) {
        int2 se = e_se[p];         // wave-uniform 8B load
        int s = se.x;
        float ea = __int_as_float(se.y);
        unsigned int pv = P[(size_t)s * 64 + d];   // gathered dword (256B/wave)
        float pf = __uint_as_float(pv << 16);
        float psv = __uint_as_float(pv & 0xffff0000u);
        float xF = fmaf(ea, wf, qf + pf);
        float xS = fmaf(ea, ws, qs + psv);
        float sig = __builtin_amdgcn_rcpf(1.f + __expf(-xF));
        float t = __expf(-fabsf(xS));
        float sp = fmaxf(xS, 0.f) + __logf(1.f + t);
        agg = fmaf(sig, sp, agg);
    }

    float inv = 1.f / (float)max(re - rb, 1);
    hout[idx] = fmaxf(hres + agg * inv, 0.f);
}

// ---------------------------------------------------------------------------
// Graph segment starts: bm sorted; gstart[b] = first node of graph b.
// ---------------------------------------------------------------------------
__global__ __launch_bounds__(256) void gstart_kernel(
    const int* __restrict__ bm, int* __restrict__ gstart, int N)
{
    int i = blockIdx.x * blockDim.x + threadIdx.x;
    if (i >= N) return;
    int b = bm[i];
    int prev = (i == 0) ? -1 : bm[i - 1];
    for (int g = prev + 1; g <= b; ++g) gstart[g] = i;
    if (i == N - 1)
        for (int g = b + 1; g <= GB; ++g) gstart[g] = N;
}

// ---------------------------------------------------------------------------
// Segmented mean pool: one block per graph, no atomics.
// ---------------------------------------------------------------------------
__global__ __launch_bounds__(256) void pool_seg_kernel(
    const float* __restrict__ h, const int* __restrict__ gstart,
    float* __restrict__ g)
{
    int b = blockIdx.x;
    int s = gstart[b], e = gstart[b + 1];
    int d = threadIdx.x & 63;
    int w = threadIdx.x >> 6;
    float acc = 0.f;
    for (int n = s + w; n < e; n += 4)
        acc += h[(size_t)n * 64 + d];
    __shared__ float lds[256];
    lds[threadIdx.x] = acc;
    __syncthreads();
    if (w == 0) {
        acc = lds[d] + lds[64 + d] + lds[128 + d] + lds[192 + d];
        g[b * 64 + d] = acc / fmaxf((float)(e - s), 1.f);
    }
}

// ---------------------------------------------------------------------------
// Fused post-MLP (3 relu layers) + final dot + bias. One wave per graph.
// ---------------------------------------------------------------------------
__global__ __launch_bounds__(256) void postmlp_kernel(
    const float* __restrict__ g,
    const float* __restrict__ W0, const float* __restrict__ b0,
    const float* __restrict__ W1, const float* __restrict__ b1,
    const float* __restrict__ W2, const float* __restrict__ b2,
    const float* __restrict__ Wfin, const float* __restrict__ bfin,
    float* __restrict__ out)
{
    int b = blockIdx.x * 4 + (threadIdx.x >> 6);   // 32 blocks x 4 waves = 128
    int d = threadIdx.x & 63;
    float h = g[(size_t)b * 64 + d];

    float acc = b0[d];
#pragma unroll
    for (int k = 0; k < 64; ++k)
        acc = fmaf(__shfl(h, k, 64), W0[k * 64 + d], acc);
    h = fmaxf(acc, 0.f);

    acc = b1[d];
#pragma unroll
    for (int k = 0; k < 64; ++k)
        acc = fmaf(__shfl(h, k, 64), W1[k * 64 + d], acc);
    h = fmaxf(acc, 0.f);

    acc = b2[d];
#pragma unroll
    for (int k = 0; k < 64; ++k)
        acc = fmaf(__shfl(h, k, 64), W2[k * 64 + d], acc);
    h = fmaxf(acc, 0.f);

    float v = h * Wfin[d];
#pragma unroll
    for (int off = 32; off >= 1; off >>= 1)
        v += __shfl_xor(v, off, 64);
    if (d == 0) out[b] = v + bfin[0];
}

extern "C" void kernel_launch(void* const* d_in, const int* in_sizes, int n_in,
                              void* d_out, int out_size, void* d_ws, size_t ws_size,
                              hipStream_t stream)
{
    const float* X      = (const float*)d_in[0];
    const int*   eidx   = (const int*)d_in[1];
    const float* ea     = (const float*)d_in[3];
    const int*   bm     = (const int*)d_in[4];
    const float* pre_W0 = (const float*)d_in[5];
    const float* pre_b0 = (const float*)d_in[6];
    const float* pre_W1 = (const float*)d_in[7];
    const float* pre_b1 = (const float*)d_in[8];
    const float* pre_W2 = (const float*)d_in[9];
    const float* pre_b2 = (const float*)d_in[10];
    const float* cg_Wf  = (const float*)d_in[11];
    const float* cg_bf  = (const float*)d_in[12];
    const float* cg_Ws  = (const float*)d_in[13];
    const float* cg_bs  = (const float*)d_in[14];
    const float* post_W0 = (const float*)d_in[15];
    const float* post_b0 = (const float*)d_in[16];
    const float* post_W1 = (const float*)d_in[17];
    const float* post_b1 = (const float*)d_in[18];
    const float* post_W2 = (const float*)d_in[19];
    const float* post_b2 = (const float*)d_in[20];
    const float* post_Wf = (const float*)d_in[21];
    const float* post_bf = (const float*)d_in[22];

    const int* src = eidx;
    const int* dst = eidx + GE;

    // ---- workspace carve-up ----
    const size_t N64 = (size_t)GN * 64;
    float* hA    = (float*)d_ws;            // N*64
    float* hB    = hA + N64;                // N*64
    unsigned int* P = (unsigned int*)(hB + N64);  // N*64 packed bf16x2
    int* deg_i   = (int*)(P + N64);         // N
    int* iscan   = deg_i + GN;              // N
    int* bsum    = iscan + GN;              // 128
    int* boff    = bsum + 128;              // 128
    int* rowptr  = boff + 128;              // N+2 (padded so e_se is 8B-aligned)
    int* cursor  = rowptr + GN + 2;         // N
    int2* e_se   = (int2*)(cursor + GN);    // E int2 (8B-aligned)
    int* gstart  = (int*)(e_se + GE);       // B+1
    float* g0    = (float*)(gstart + GB + 1); // B*64 (8192 floats, keeps 8B align)
    float* Q     = g0 + (size_t)GB * 64;    // N*128 fp32 (qf,qs) pairs

    const int TPB = 256;
    int gridE  = (GE + TPB - 1) / TPB;
    int gridN  = (GN + TPB - 1) / TPB;         // 391 (lane=node grid)
    int gridP  = (GN + 127) / 128;             // 782 (R=2 col-split dense grid)
    int gridND = ((GN * 64) + TPB - 1) / TPB;  // 25000 (edge grid)
    int scanBlocks = (GN + 1023) / 1024;       // 98

    // per-layer weight pointers
    const float* Wf0 = cg_Wf;
    const float* Ws0 = cg_Ws;
    const float* Wf1 = cg_Wf + (size_t)1 * GZ * GD;
    const float* Ws1 = cg_Ws + (size_t)1 * GZ * GD;
    const float* Wf2 = cg_Wf + (size_t)2 * GZ * GD;
    const float* Ws2 = cg_Ws + (size_t)2 * GZ * GD;

    // fused pre-MLP (R14 col-split) + P0 + Q0
    premlp_kernel<<<gridP, TPB, 0, stream>>>(
        X, pre_W0, pre_b0, pre_W1, pre_b1, pre_W2, pre_b2,
        Wf0, Ws0, Wf0 + 64 * 64, Ws0 + 64 * 64, cg_bf, cg_bs,
        hA, P, Q, GN);

    // degree + CSR build
    hipMemsetAsync(deg_i, 0, GN * sizeof(int), stream);
    deg_kernel<<<gridE, TPB, 0, stream>>>(dst, deg_i, GE);
    scanA_kernel<<<scanBlocks, 1024, 0, stream>>>(deg_i, iscan, bsum, GN);
    scanB_kernel<<<1, 128, 0, stream>>>(bsum, boff, scanBlocks);
    scanC_kernel<<<gridN, TPB, 0, stream>>>(iscan, boff, deg_i, rowptr, cursor, GN);
    escatter_kernel<<<gridE, TPB, 0, stream>>>(src, dst, ea, cursor, e_se, GE);

    // graph segment starts (bm sorted)
    gstart_kernel<<<gridN, TPB, 0, stream>>>(bm, gstart, GN);

    // CGConv layers: node-wave edge pass + fused P/Q projection for next layer
    edge_kernel<<<gridND, TPB, 0, stream>>>(
        hA, rowptr, e_se, P, Q, Wf0, Ws0, hB);
    pjq_kernel<<<gridP, TPB, 0, stream>>>(
        hB, Wf1, Ws1, cg_bf + GD, cg_bs + GD, P, Q, GN);
    edge_kernel<<<gridND, TPB, 0, stream>>>(
        hB, rowptr, e_se, P, Q, Wf1, Ws1, hA);
    pjq_kernel<<<gridP, TPB, 0, stream>>>(
        hA, Wf2, Ws2, cg_bf + 2 * GD, cg_bs + 2 * GD, P, Q, GN);
    edge_kernel<<<gridND, TPB, 0, stream>>>(
        hA, rowptr, e_se, P, Q, Wf2, Ws2, hB);

    // segmented mean pool (no atomics)
    pool_seg_kernel<<<GB, TPB, 0, stream>>>(hB, gstart, g0);

    // fused post-MLP + final projection
    postmlp_kernel<<<GB / 4, TPB, 0, stream>>>(
        g0, post_W0, post_b0, post_W1, post_b1, post_W2, post_b2,
        post_Wf, post_bf, (float*)d_out);
}